// Round 2
// 428.627 us; speedup vs baseline: 1.0294x; 1.0294x over previous
//
#include <hip/hip_runtime.h>
#include <stdint.h>

#define DEVI __device__ __forceinline__

typedef __attribute__((ext_vector_type(8))) short short8;
typedef __attribute__((ext_vector_type(4))) float f32x4;
typedef __attribute__((ext_vector_type(4))) unsigned int u32x4;

static constexpr int Bn = 2;
static constexpr int Tn = 2048;
static constexpr int Cn = 2048;
static constexpr int NH = 16;
static constexpr int HD = 128;
static constexpr int Kdim = 2048;

DEVI unsigned short f2bf(float f) {
  union { float f; unsigned u; } v; v.f = f;
  return (unsigned short)((v.u + 0x7FFFu + ((v.u >> 16) & 1u)) >> 16);
}

DEVI void gload_lds16(const void* g, void* l) {
  __builtin_amdgcn_global_load_lds(
      (const __attribute__((address_space(1))) void*)g,
      (__attribute__((address_space(3))) void*)l, 16, 0, 0);
}

// ---------------- cast fp32 -> bf16 (RNE) ----------------
__global__ __launch_bounds__(256) void cast_bf16_kernel(
    const float* __restrict__ src, unsigned short* __restrict__ dst, int n) {
  int idx = (blockIdx.x * blockDim.x + threadIdx.x) * 4;
  const int stride = gridDim.x * blockDim.x * 4;
  for (; idx < n; idx += stride) {
    f32x4 f = *(const f32x4*)(src + idx);
    unsigned short o[4];
    o[0] = f2bf(f[0]); o[1] = f2bf(f[1]); o[2] = f2bf(f[2]); o[3] = f2bf(f[3]);
    *(unsigned long long*)(dst + idx) = *(const unsigned long long*)o;
  }
}

// one dispatch for all 4 weight matrices (blockIdx.y selects)
__global__ __launch_bounds__(256) void cast4_kernel(
    const float* __restrict__ s0, const float* __restrict__ s1,
    const float* __restrict__ s2, const float* __restrict__ s3,
    unsigned short* __restrict__ d0, unsigned short* __restrict__ d1,
    unsigned short* __restrict__ d2, unsigned short* __restrict__ d3, int n) {
  const int w = blockIdx.y;
  const float* src = (w == 0) ? s0 : (w == 1) ? s1 : (w == 2) ? s2 : s3;
  unsigned short* dst = (w == 0) ? d0 : (w == 1) ? d1 : (w == 2) ? d2 : d3;
  int idx = (blockIdx.x * blockDim.x + threadIdx.x) * 4;
  const int stride = gridDim.x * blockDim.x * 4;
  for (; idx < n; idx += stride) {
    f32x4 f = *(const f32x4*)(src + idx);
    unsigned short o[4];
    o[0] = f2bf(f[0]); o[1] = f2bf(f[1]); o[2] = f2bf(f[2]); o[3] = f2bf(f[3]);
    *(unsigned long long*)(dst + idx) = *(const unsigned long long*)o;
  }
}

// ---------------- fused QKV projection GEMM: 256^2 8-phase ----------------
// BM=BN=256, BK=64, 8 waves (2M x 4N), 512 threads, 128 KB LDS (2 bufs of
// one K-tile each: A 256x64 + B 256x64). Per K-tile: 4 phases of 16 MFMA,
// builtin s_barrier + counted vmcnt(4) at tile boundary (never 0 in steady
// state), setprio(1) around MFMA clusters (T5). LDS chunk-XOR swizzle
// (phys 16B chunk = logical ^ (row&7)) applied via pre-swizzled global
// source (gload_lds dest stays linear) -> conflict-free ds_read_b128.
// Staging schedule per K-tile t: ph0/ph1 stage A(t+1) into buf[t+1&1]
// (its A region was consumed at t-1 ph2); ph2/ph3 stage B(t+2) into
// buf[t&1] (B(t) fully consumed after ph1 barrier). vmcnt(4) at boundary
// leaves exactly B(t+2)'s 4 loads in flight.
// Q/K out: (B,H,T,D) bf16 scattered; V out: (B,H,D,T) bf16 (pre-transposed).
#define QKV_BAR() __builtin_amdgcn_s_barrier()
#define QKV_MFMA(d, a, b) d = __builtin_amdgcn_mfma_f32_16x16x32_bf16(a, b, d, 0, 0, 0)

__global__ __launch_bounds__(512, 2) void gemm_qkv_8ph_kernel(
    const unsigned short* __restrict__ X,
    const unsigned short* __restrict__ Wq_, const unsigned short* __restrict__ Wk_,
    const unsigned short* __restrict__ Wv_,
    const float* __restrict__ bq_, const float* __restrict__ bk_, const float* __restrict__ bv_,
    unsigned short* __restrict__ Qo, unsigned short* __restrict__ Ko,
    unsigned short* __restrict__ Vo) {
  constexpr int NT = Kdim / 64;  // 32 K-tiles
  __shared__ unsigned short L[2][2][16384];  // [buf][A=0/B=1][256*64], 128 KB

  const int tid = threadIdx.x;
  const int wave = tid >> 6, lane = tid & 63;
  const int wm = wave >> 2, wn = wave & 3;      // 2M x 4N wave grid
  const int quad = lane >> 4, lr = lane & 15;

  // XCD-bijective swizzle: 384 blocks = 8 XCDs x 48 contiguous (2 m-rows)
  const int flat = (int)blockIdx.x + 24 * (int)blockIdx.y;
  const int swz = (flat & 7) * 48 + (flat >> 3);
  const int bx = swz % 24, by = swz / 24;
  const int sel = bx >> 3;              // 0=Q 1=K 2=V
  const int n0 = (bx & 7) * 256;
  const int m0 = by * 256;
  const unsigned short* W = (sel == 0) ? Wq_ : (sel == 1) ? Wk_ : Wv_;
  const float* bias = (sel == 0) ? bq_ : (sel == 1) ? bk_ : bv_;

  f32x4 acc[8][4];
  const f32x4 zero4 = {0.f, 0.f, 0.f, 0.f};
#pragma unroll
  for (int i = 0; i < 8; ++i)
#pragma unroll
    for (int j = 0; j < 4; ++j) acc[i][j] = zero4;

  // staging: thread -> (row = tid>>3, phys chunk = tid&7); source chunk
  // pre-swizzled so LDS (linear dest) holds phys = logical ^ (row&7)
  const int srow = tid >> 3;                      // 0..63
  const int schunk = (tid & 7) ^ (srow & 7);
  const unsigned short* Asrc = X + (size_t)(m0 + srow) * Kdim + schunk * 8;
  const unsigned short* Bsrc = W + (size_t)(n0 + srow) * Kdim + schunk * 8;

  auto STAGE_A = [&](int buf, int h, int t) {
    unsigned short* d = &L[buf][0][h * 8192 + tid * 8];
    const unsigned short* s = Asrc + (size_t)(h * 128) * Kdim + t * 64;
    gload_lds16(s, d);
    gload_lds16(s + (size_t)64 * Kdim, d + 4096);
  };
  auto STAGE_B = [&](int buf, int h, int t) {
    unsigned short* d = &L[buf][1][h * 8192 + tid * 8];
    const unsigned short* s = Bsrc + (size_t)(h * 128) * Kdim + t * 64;
    gload_lds16(s, d);
    gload_lds16(s + (size_t)64 * Kdim, d + 4096);
  };

  // frag read addressing: row = band + blk*16 + lr; phys chunk =
  // (ks*4 + quad) ^ (lr&7)  (row&7 == lr&7 since 16 | row-base)
  const int pc0 = (quad) ^ (lr & 7);
  const int pc1 = (4 + quad) ^ (lr & 7);
  const int aoff = (wm * 128 + lr) * 64;
  const int boff = (wn * 64 + lr) * 64;
#define RDA(mi, pc) (*(const short8*)&L[cur][0][aoff + (mi) * 1024 + (pc) * 8])
#define RDB(ni, pc) (*(const short8*)&L[cur][1][boff + (ni) * 1024 + (pc) * 8])

  // prologue: A0,B0 -> buf0; B1 -> buf1; drain all but B1's 4 loads
  STAGE_A(0, 0, 0); STAGE_A(0, 1, 0);
  STAGE_B(0, 0, 0); STAGE_B(0, 1, 0);
  STAGE_B(1, 0, 1); STAGE_B(1, 1, 1);
  asm volatile("s_waitcnt vmcnt(4)" ::: "memory");
  QKV_BAR();

  short8 Af[4][2], B01[2][2], B23[2][2];

  for (int t = 0; t < NT; ++t) {
    const int cur = t & 1, nxt = cur ^ 1;
    // ---- phase 0: read A[0..3]+B[0..1]; stage A(t+1).h0; mfma m0-3 x n0-1
#pragma unroll
    for (int m = 0; m < 4; ++m) { Af[m][0] = RDA(m, pc0); Af[m][1] = RDA(m, pc1); }
#pragma unroll
    for (int n = 0; n < 2; ++n) { B01[n][0] = RDB(n, pc0); B01[n][1] = RDB(n, pc1); }
    if (t + 1 < NT) STAGE_A(nxt, 0, t + 1);
    QKV_BAR();
    __builtin_amdgcn_s_setprio(1);
#pragma unroll
    for (int m = 0; m < 4; ++m)
#pragma unroll
      for (int n = 0; n < 2; ++n) {
        QKV_MFMA(acc[m][n], Af[m][0], B01[n][0]);
        QKV_MFMA(acc[m][n], Af[m][1], B01[n][1]);
      }
    __builtin_amdgcn_s_setprio(0);
    QKV_BAR();
    // ---- phase 1: read B[2..3]; stage A(t+1).h1; mfma m0-3 x n2-3
#pragma unroll
    for (int n = 0; n < 2; ++n) { B23[n][0] = RDB(n + 2, pc0); B23[n][1] = RDB(n + 2, pc1); }
    if (t + 1 < NT) STAGE_A(nxt, 1, t + 1);
    QKV_BAR();
    __builtin_amdgcn_s_setprio(1);
#pragma unroll
    for (int m = 0; m < 4; ++m)
#pragma unroll
      for (int n = 0; n < 2; ++n) {
        QKV_MFMA(acc[m][n + 2], Af[m][0], B23[n][0]);
        QKV_MFMA(acc[m][n + 2], Af[m][1], B23[n][1]);
      }
    __builtin_amdgcn_s_setprio(0);
    QKV_BAR();
    // ---- phase 2: read A[4..7]; stage B(t+2).h0; mfma m4-7 x n0-1
#pragma unroll
    for (int m = 0; m < 4; ++m) { Af[m][0] = RDA(m + 4, pc0); Af[m][1] = RDA(m + 4, pc1); }
    if (t + 2 < NT) STAGE_B(cur, 0, t + 2);
    QKV_BAR();
    __builtin_amdgcn_s_setprio(1);
#pragma unroll
    for (int m = 0; m < 4; ++m)
#pragma unroll
      for (int n = 0; n < 2; ++n) {
        QKV_MFMA(acc[m + 4][n], Af[m][0], B01[n][0]);
        QKV_MFMA(acc[m + 4][n], Af[m][1], B01[n][1]);
      }
    __builtin_amdgcn_s_setprio(0);
    QKV_BAR();
    // ---- phase 3: no reads; stage B(t+2).h1; mfma m4-7 x n2-3
    if (t + 2 < NT) STAGE_B(cur, 1, t + 2);
    QKV_BAR();
    __builtin_amdgcn_s_setprio(1);
#pragma unroll
    for (int m = 0; m < 4; ++m)
#pragma unroll
      for (int n = 0; n < 2; ++n) {
        QKV_MFMA(acc[m + 4][n + 2], Af[m][0], B23[n][0]);
        QKV_MFMA(acc[m + 4][n + 2], Af[m][1], B23[n][1]);
      }
    __builtin_amdgcn_s_setprio(0);
    if (t < NT - 2) { asm volatile("s_waitcnt vmcnt(4)" ::: "memory"); }
    else            { asm volatile("s_waitcnt vmcnt(0)" ::: "memory"); }
    QKV_BAR();
  }
#undef RDA
#undef RDB

  // ---- epilogue ----
  if (sel == 2) {
    // V^T: out[(b,h,d,t)]; 4 consecutive t per acc quad -> 8B stores
#pragma unroll
    for (int ni = 0; ni < 4; ++ni) {
      const int n = n0 + wn * 64 + ni * 16 + lr;
      const float bv = bias[n];
      const int h = n >> 7, d = n & 127;
#pragma unroll
      for (int mi = 0; mi < 8; ++mi) {
        const int m = m0 + wm * 128 + mi * 16 + quad * 4;
        const int b = m >> 11, tt = m & 2047;
        unsigned short o4[4];
#pragma unroll
        for (int r = 0; r < 4; ++r) o4[r] = f2bf(acc[mi][ni][r] + bv);
        *(unsigned long long*)&Vo[(((size_t)(b * NH + h)) * HD + d) * Tn + tt] =
            *(const unsigned long long*)o4;
      }
    }
  } else {
    unsigned short* Out = (sel == 0) ? Qo : Ko;
#pragma unroll
    for (int ni = 0; ni < 4; ++ni) {
      const int n = n0 + wn * 64 + ni * 16 + lr;
      const float bv = bias[n];
      const int h = n >> 7, d = n & 127;
#pragma unroll
      for (int mi = 0; mi < 8; ++mi) {
#pragma unroll
        for (int r = 0; r < 4; ++r) {
          const int m = m0 + wm * 128 + mi * 16 + quad * 4 + r;
          const int b = m >> 11, tt = m & 2047;
          Out[(((size_t)(b * NH + h)) * Tn + tt) * HD + d] = f2bf(acc[mi][ni][r] + bv);
        }
      }
    }
  }
}

// ---------------- output projection GEMM (fp32 out) ----------------
// grid (16, 16, 2): x = n (fastest), y = m, z = batch. BK=32 + XOR swizzle.
__global__ __launch_bounds__(256) void gemm_proj_kernel(
    const unsigned short* __restrict__ Aall,  // (B, 2048, 2048) = O^T rows (h*128+d), cols t
    const unsigned short* __restrict__ W,     // Wp (N=C, K) bf16
    const float* __restrict__ bias,
    float* __restrict__ Y) {                  // (B, T, C) fp32
  __shared__ unsigned short As[128 * 32];
  __shared__ unsigned short Bs[128 * 32];
  const int tid = threadIdx.x;
  const int wave = tid >> 6, lane = tid & 63;
  const int wm = wave >> 1, wn = wave & 1;
  const int quad = lane >> 4, lr = lane & 15;

  const int m0 = blockIdx.y * 128, n0 = blockIdx.x * 128;
  const int bz = blockIdx.z;
  const unsigned short* A = Aall + (size_t)bz * Cn * Tn;

  f32x4 acc[4][4];
  const f32x4 zero4 = {0.f, 0.f, 0.f, 0.f};
#pragma unroll
  for (int i = 0; i < 4; ++i)
#pragma unroll
    for (int j = 0; j < 4; ++j) acc[i][j] = zero4;

  const int srow = tid >> 2;
  const int scol = (((tid & 3) ^ ((srow >> 1) & 3)) * 8);
  const unsigned short* Ag = A + (size_t)(m0 + srow) * Kdim + scol;
  const unsigned short* Bg = W + (size_t)(n0 + srow) * Kdim + scol;
  unsigned short* Al = &As[tid * 8];
  unsigned short* Bl = &Bs[tid * 8];
  const int fsw = (quad ^ ((lr >> 1) & 3)) * 8;

  for (int k0 = 0; k0 < Kdim; k0 += 32) {
    gload_lds16(Ag + k0, Al);
    gload_lds16(Ag + (size_t)64 * Kdim + k0, Al + 2048);
    gload_lds16(Bg + k0, Bl);
    gload_lds16(Bg + (size_t)64 * Kdim + k0, Bl + 2048);
    __syncthreads();
    short8 af[4], bf[4];
#pragma unroll
    for (int mi = 0; mi < 4; ++mi)
      af[mi] = *(const short8*)&As[(wm * 64 + mi * 16 + lr) * 32 + fsw];
#pragma unroll
    for (int ni = 0; ni < 4; ++ni)
      bf[ni] = *(const short8*)&Bs[(wn * 64 + ni * 16 + lr) * 32 + fsw];
#pragma unroll
    for (int mi = 0; mi < 4; ++mi)
#pragma unroll
      for (int ni = 0; ni < 4; ++ni)
        acc[mi][ni] = __builtin_amdgcn_mfma_f32_16x16x32_bf16(af[mi], bf[ni], acc[mi][ni], 0, 0, 0);
    __syncthreads();
  }

#pragma unroll
  for (int ni = 0; ni < 4; ++ni) {
    const int n = n0 + wn * 64 + ni * 16 + lr;
    const float bv = bias[n];
#pragma unroll
    for (int mi = 0; mi < 4; ++mi) {
#pragma unroll
      for (int r = 0; r < 4; ++r) {
        const int m = m0 + wm * 64 + mi * 16 + quad * 4 + r;
        Y[((size_t)bz * Tn + m) * Cn + n] = acc[mi][ni][r] + bv;
      }
    }
  }
}

// ---------------- flash attention (fixed-max softmax, paired q-tiles) ---
// Q,K: (BH, T, HD) bf16; V: (BH, HD, T) bf16 (written transposed by QKV).
// Output: O^T (B, H*HD, T) bf16 directly (epilogue transposes via Ps LDS).
__global__ __launch_bounds__(256, 1) void attn_kernel(
    const unsigned short* __restrict__ Q,
    const unsigned short* __restrict__ K,
    const unsigned short* __restrict__ V,
    unsigned short* __restrict__ Ot) {
  constexpr int KST = 136;
  constexpr int VST = 136;   // 144 x 136 (rows 128..143 = ones)
  constexpr int PST = 136;   // 128 x 136 (4 waves x 32 rows)
  __shared__ unsigned short Ks[128 * KST];
  __shared__ unsigned short Vs[144 * VST];
  __shared__ unsigned short Ps[128 * PST];

  const int tid = threadIdx.x;
  const int wave = tid >> 6, lane = tid & 63;
  const int quad = lane >> 4, lr = lane & 15;
  const int bh = blockIdx.y;
  const float SL = 0.08838834764831845f * 1.4426950408889634f;  // scale*log2(e)

  const unsigned short* Kp = K + (size_t)bh * Tn * HD;
  const unsigned short* Vp = V + (size_t)bh * HD * Tn;
  unsigned short* Pw = &Ps[wave * 32 * PST];

  for (int i = tid; i < 16 * VST; i += 256) Vs[128 * VST + i] = 0x3F80;

  const f32x4 zero4 = {0.f, 0.f, 0.f, 0.f};
#pragma unroll 1
  for (int half = 0; half < 2; ++half) {
    const int jt = half ? (15 - (int)blockIdx.x) : (int)blockIdx.x;
    const int q0 = jt * 128;

    const unsigned short* Qp = Q + ((size_t)bh * Tn + q0 + wave * 32) * HD;
    short8 qf[2][4];
#pragma unroll
    for (int mi = 0; mi < 2; ++mi)
#pragma unroll
      for (int ks = 0; ks < 4; ++ks)
        qf[mi][ks] = *(const short8*)&Qp[(mi * 16 + lr) * HD + ks * 32 + quad * 8];

    f32x4 oacc[2][9];
#pragma unroll
    for (int mi = 0; mi < 2; ++mi)
#pragma unroll
      for (int nd = 0; nd < 9; ++nd) oacc[mi][nd] = zero4;

    const int nch = q0 / 128 + 1;
    for (int c = 0; c < nch; ++c) {
      const int k0 = c * 128;
      {
        const int r = tid >> 1;
        const int cc = (tid & 1) * 64;
        const unsigned short* kg = &Kp[(size_t)(k0 + r) * HD + cc];
        const unsigned short* vg = &Vp[(size_t)r * Tn + k0 + cc];
        unsigned short* kl = &Ks[r * KST + cc];
        unsigned short* vl = &Vs[r * VST + cc];
#pragma unroll
        for (int p = 0; p < 8; ++p) {
          *(u32x4*)(kl + p * 8) = *(const u32x4*)(kg + p * 8);
          *(u32x4*)(vl + p * 8) = *(const u32x4*)(vg + p * 8);
        }
      }
      __syncthreads();

      f32x4 sa[2][8];
#pragma unroll
      for (int mi = 0; mi < 2; ++mi)
#pragma unroll
        for (int nt = 0; nt < 8; ++nt) sa[mi][nt] = zero4;
#pragma unroll
      for (int nt = 0; nt < 8; ++nt) {
        short8 kf[4];
#pragma unroll
        for (int ks = 0; ks < 4; ++ks)
          kf[ks] = *(const short8*)&Ks[(nt * 16 + lr) * KST + ks * 32 + quad * 8];
#pragma unroll
        for (int mi = 0; mi < 2; ++mi)
#pragma unroll
          for (int ks = 0; ks < 4; ++ks)
            sa[mi][nt] = __builtin_amdgcn_mfma_f32_16x16x32_bf16(qf[mi][ks], kf[ks], sa[mi][nt], 0, 0, 0);
      }

      if (k0 == q0) {
#pragma unroll
        for (int mi = 0; mi < 2; ++mi)
#pragma unroll
          for (int nt = 0; nt < 8; ++nt)
#pragma unroll
            for (int r = 0; r < 4; ++r) {
              const int qg = q0 + wave * 32 + mi * 16 + quad * 4 + r;
              const int kg = k0 + nt * 16 + lr;
              if (kg > qg) sa[mi][nt][r] = -3.0e38f;
            }
      }

#pragma unroll
      for (int mi = 0; mi < 2; ++mi)
#pragma unroll
        for (int nt = 0; nt < 8; ++nt)
#pragma unroll
          for (int r = 0; r < 4; ++r) {
            const float p = __builtin_amdgcn_exp2f(sa[mi][nt][r] * SL);
            Pw[(mi * 16 + quad * 4 + r) * PST + nt * 16 + lr] = f2bf(p);
          }

#pragma unroll
      for (int kt = 0; kt < 4; ++kt) {
        short8 pf[2];
#pragma unroll
        for (int mi = 0; mi < 2; ++mi)
          pf[mi] = *(const short8*)&Pw[(mi * 16 + lr) * PST + kt * 32 + quad * 8];
#pragma unroll
        for (int nd = 0; nd < 9; ++nd) {
          short8 vf = *(const short8*)&Vs[(nd * 16 + lr) * VST + kt * 32 + quad * 8];
#pragma unroll
          for (int mi = 0; mi < 2; ++mi)
            oacc[mi][nd] = __builtin_amdgcn_mfma_f32_16x16x32_bf16(pf[mi], vf, oacc[mi][nd], 0, 0, 0);
        }
      }
      __syncthreads();
    }

    // epilogue: normalize, stage into Ps (t-major), write O^T coalesced
#pragma unroll
    for (int mi = 0; mi < 2; ++mi)
#pragma unroll
      for (int r = 0; r < 4; ++r) {
        const float rl = 1.0f / oacc[mi][8][r];
        const int tl = wave * 32 + mi * 16 + quad * 4 + r;
#pragma unroll
        for (int nd = 0; nd < 8; ++nd)
          Ps[tl * PST + nd * 16 + lr] = f2bf(oacc[mi][nd][r] * rl);
      }
    __syncthreads();
    {
      unsigned short* Od = Ot + (size_t)bh * HD * Tn + q0;  // row = d, stride Tn
#pragma unroll
      for (int p = 0; p < 8; ++p) {
        const int d = p * 16 + (tid >> 4);
        const int t8 = (tid & 15) * 8;
        alignas(16) unsigned short v[8];
#pragma unroll
        for (int j = 0; j < 8; ++j) v[j] = Ps[(t8 + j) * PST + d];
        *(u32x4*)&Od[(size_t)d * Tn + t8] = *(const u32x4*)v;
      }
    }
    __syncthreads();
  }
}

extern "C" void kernel_launch(void* const* d_in, const int* in_sizes, int n_in,
                              void* d_out, int out_size, void* d_ws, size_t ws_size,
                              hipStream_t stream) {
  const float* x  = (const float*)d_in[0];
  const float* Wq = (const float*)d_in[1];
  const float* bq = (const float*)d_in[2];
  const float* Wk = (const float*)d_in[3];
  const float* bk = (const float*)d_in[4];
  const float* Wv = (const float*)d_in[5];
  const float* bv = (const float*)d_in[6];
  const float* Wp = (const float*)d_in[7];
  const float* bp = (const float*)d_in[8];
  float* out = (float*)d_out;

  char* ws = (char*)d_ws;
  const size_t MB = 1ull << 20;
  unsigned short* Xbf = (unsigned short*)(ws);             // 16MB
  unsigned short* Wqb = (unsigned short*)(ws + 16 * MB);   // 8MB each
  unsigned short* Wkb = (unsigned short*)(ws + 24 * MB);
  unsigned short* Wvb = (unsigned short*)(ws + 32 * MB);
  unsigned short* Wpb = (unsigned short*)(ws + 40 * MB);
  unsigned short* Qb  = (unsigned short*)(ws + 48 * MB);   // 16MB
  unsigned short* Kb  = (unsigned short*)(ws + 64 * MB);   // 16MB
  unsigned short* Vtb = (unsigned short*)(ws + 80 * MB);   // 16MB (B,H,D,T)
  unsigned short* Otb = (unsigned short*)(ws + 96 * MB);   // 16MB (B,H*D,T)

  cast_bf16_kernel<<<dim3(1024), dim3(256), 0, stream>>>(x, Xbf, Bn * Tn * Cn);
  cast4_kernel<<<dim3(512, 4), dim3(256), 0, stream>>>(
      Wq, Wk, Wv, Wp, Wqb, Wkb, Wvb, Wpb, Cn * Cn);

  gemm_qkv_8ph_kernel<<<dim3(24, 16), dim3(512), 0, stream>>>(
      Xbf, Wqb, Wkb, Wvb, bq, bk, bv, Qb, Kb, Vtb);

  attn_kernel<<<dim3(8, Bn * NH), dim3(256), 0, stream>>>(Qb, Kb, Vtb, Otb);

  gemm_proj_kernel<<<dim3(16, 16, 2), dim3(256), 0, stream>>>(Otb, Wpb, bp, out);
}

// Round 3
// 416.882 us; speedup vs baseline: 1.0584x; 1.0282x over previous
//
#include <hip/hip_runtime.h>
#include <stdint.h>

#define DEVI __device__ __forceinline__

typedef __attribute__((ext_vector_type(8))) short short8;
typedef __attribute__((ext_vector_type(4))) float f32x4;
typedef __attribute__((ext_vector_type(4))) unsigned int u32x4;

static constexpr int Bn = 2;
static constexpr int Tn = 2048;
static constexpr int Cn = 2048;
static constexpr int NH = 16;
static constexpr int HD = 128;
static constexpr int Kdim = 2048;

DEVI unsigned short f2bf(float f) {
  union { float f; unsigned u; } v; v.f = f;
  return (unsigned short)((v.u + 0x7FFFu + ((v.u >> 16) & 1u)) >> 16);
}

DEVI void gload_lds16(const void* g, void* l) {
  __builtin_amdgcn_global_load_lds(
      (const __attribute__((address_space(1))) void*)g,
      (__attribute__((address_space(3))) void*)l, 16, 0, 0);
}

// ---------------- cast fp32 -> bf16 (RNE) ----------------
__global__ __launch_bounds__(256) void cast_bf16_kernel(
    const float* __restrict__ src, unsigned short* __restrict__ dst, int n) {
  int idx = (blockIdx.x * blockDim.x + threadIdx.x) * 4;
  const int stride = gridDim.x * blockDim.x * 4;
  for (; idx < n; idx += stride) {
    f32x4 f = *(const f32x4*)(src + idx);
    unsigned short o[4];
    o[0] = f2bf(f[0]); o[1] = f2bf(f[1]); o[2] = f2bf(f[2]); o[3] = f2bf(f[3]);
    *(unsigned long long*)(dst + idx) = *(const unsigned long long*)o;
  }
}

// one dispatch for all 4 weight matrices (blockIdx.y selects)
__global__ __launch_bounds__(256) void cast4_kernel(
    const float* __restrict__ s0, const float* __restrict__ s1,
    const float* __restrict__ s2, const float* __restrict__ s3,
    unsigned short* __restrict__ d0, unsigned short* __restrict__ d1,
    unsigned short* __restrict__ d2, unsigned short* __restrict__ d3, int n) {
  const int w = blockIdx.y;
  const float* src = (w == 0) ? s0 : (w == 1) ? s1 : (w == 2) ? s2 : s3;
  unsigned short* dst = (w == 0) ? d0 : (w == 1) ? d1 : (w == 2) ? d2 : d3;
  int idx = (blockIdx.x * blockDim.x + threadIdx.x) * 4;
  const int stride = gridDim.x * blockDim.x * 4;
  for (; idx < n; idx += stride) {
    f32x4 f = *(const f32x4*)(src + idx);
    unsigned short o[4];
    o[0] = f2bf(f[0]); o[1] = f2bf(f[1]); o[2] = f2bf(f[2]); o[3] = f2bf(f[3]);
    *(unsigned long long*)(dst + idx) = *(const unsigned long long*)o;
  }
}

// ---------------- fused QKV projection GEMM: 256^2 8-phase ----------------
// BM=BN=256, BK=64, 8 waves (2M x 4N), 512 threads, 128 KB LDS (2 bufs of
// one K-tile each: A 256x64 + B 256x64). Per K-tile: 4 phases of 16 MFMA,
// builtin s_barrier + counted vmcnt(4) at tile boundary (never 0 in steady
// state), setprio(1) around MFMA clusters (T5). LDS chunk-XOR swizzle
// (phys 16B chunk = logical ^ (row&7)) applied via pre-swizzled global
// source (gload_lds dest stays linear) -> conflict-free ds_read_b128.
// NOTE (r2 counters): 1 block/CU + 384 blocks = 1.5 dispatch rounds ->
// structural tail; retile deferred.
#define QKV_BAR() __builtin_amdgcn_s_barrier()
#define QKV_MFMA(d, a, b) d = __builtin_amdgcn_mfma_f32_16x16x32_bf16(a, b, d, 0, 0, 0)

__global__ __launch_bounds__(512, 2) void gemm_qkv_8ph_kernel(
    const unsigned short* __restrict__ X,
    const unsigned short* __restrict__ Wq_, const unsigned short* __restrict__ Wk_,
    const unsigned short* __restrict__ Wv_,
    const float* __restrict__ bq_, const float* __restrict__ bk_, const float* __restrict__ bv_,
    unsigned short* __restrict__ Qo, unsigned short* __restrict__ Ko,
    unsigned short* __restrict__ Vo) {
  constexpr int NT = Kdim / 64;  // 32 K-tiles
  __shared__ unsigned short L[2][2][16384];  // [buf][A=0/B=1][256*64], 128 KB

  const int tid = threadIdx.x;
  const int wave = tid >> 6, lane = tid & 63;
  const int wm = wave >> 2, wn = wave & 3;      // 2M x 4N wave grid
  const int quad = lane >> 4, lr = lane & 15;

  // XCD-bijective swizzle: 384 blocks = 8 XCDs x 48 contiguous (2 m-rows)
  const int flat = (int)blockIdx.x + 24 * (int)blockIdx.y;
  const int swz = (flat & 7) * 48 + (flat >> 3);
  const int bx = swz % 24, by = swz / 24;
  const int sel = bx >> 3;              // 0=Q 1=K 2=V
  const int n0 = (bx & 7) * 256;
  const int m0 = by * 256;
  const unsigned short* W = (sel == 0) ? Wq_ : (sel == 1) ? Wk_ : Wv_;
  const float* bias = (sel == 0) ? bq_ : (sel == 1) ? bk_ : bv_;

  f32x4 acc[8][4];
  const f32x4 zero4 = {0.f, 0.f, 0.f, 0.f};
#pragma unroll
  for (int i = 0; i < 8; ++i)
#pragma unroll
    for (int j = 0; j < 4; ++j) acc[i][j] = zero4;

  // staging: thread -> (row = tid>>3, phys chunk = tid&7); source chunk
  // pre-swizzled so LDS (linear dest) holds phys = logical ^ (row&7)
  const int srow = tid >> 3;                      // 0..63
  const int schunk = (tid & 7) ^ (srow & 7);
  const unsigned short* Asrc = X + (size_t)(m0 + srow) * Kdim + schunk * 8;
  const unsigned short* Bsrc = W + (size_t)(n0 + srow) * Kdim + schunk * 8;

  auto STAGE_A = [&](int buf, int h, int t) {
    unsigned short* d = &L[buf][0][h * 8192 + tid * 8];
    const unsigned short* s = Asrc + (size_t)(h * 128) * Kdim + t * 64;
    gload_lds16(s, d);
    gload_lds16(s + (size_t)64 * Kdim, d + 4096);
  };
  auto STAGE_B = [&](int buf, int h, int t) {
    unsigned short* d = &L[buf][1][h * 8192 + tid * 8];
    const unsigned short* s = Bsrc + (size_t)(h * 128) * Kdim + t * 64;
    gload_lds16(s, d);
    gload_lds16(s + (size_t)64 * Kdim, d + 4096);
  };

  // frag read addressing: row = band + blk*16 + lr; phys chunk =
  // (ks*4 + quad) ^ (lr&7)  (row&7 == lr&7 since 16 | row-base)
  const int pc0 = (quad) ^ (lr & 7);
  const int pc1 = (4 + quad) ^ (lr & 7);
  const int aoff = (wm * 128 + lr) * 64;
  const int boff = (wn * 64 + lr) * 64;
#define RDA(mi, pc) (*(const short8*)&L[cur][0][aoff + (mi) * 1024 + (pc) * 8])
#define RDB(ni, pc) (*(const short8*)&L[cur][1][boff + (ni) * 1024 + (pc) * 8])

  // prologue: A0,B0 -> buf0; B1 -> buf1; drain all but B1's 4 loads
  STAGE_A(0, 0, 0); STAGE_A(0, 1, 0);
  STAGE_B(0, 0, 0); STAGE_B(0, 1, 0);
  STAGE_B(1, 0, 1); STAGE_B(1, 1, 1);
  asm volatile("s_waitcnt vmcnt(4)" ::: "memory");
  QKV_BAR();

  short8 Af[4][2], B01[2][2], B23[2][2];

  for (int t = 0; t < NT; ++t) {
    const int cur = t & 1, nxt = cur ^ 1;
    // ---- phase 0: read A[0..3]+B[0..1]; stage A(t+1).h0; mfma m0-3 x n0-1
#pragma unroll
    for (int m = 0; m < 4; ++m) { Af[m][0] = RDA(m, pc0); Af[m][1] = RDA(m, pc1); }
#pragma unroll
    for (int n = 0; n < 2; ++n) { B01[n][0] = RDB(n, pc0); B01[n][1] = RDB(n, pc1); }
    if (t + 1 < NT) STAGE_A(nxt, 0, t + 1);
    QKV_BAR();
    __builtin_amdgcn_s_setprio(1);
#pragma unroll
    for (int m = 0; m < 4; ++m)
#pragma unroll
      for (int n = 0; n < 2; ++n) {
        QKV_MFMA(acc[m][n], Af[m][0], B01[n][0]);
        QKV_MFMA(acc[m][n], Af[m][1], B01[n][1]);
      }
    __builtin_amdgcn_s_setprio(0);
    QKV_BAR();
    // ---- phase 1: read B[2..3]; stage A(t+1).h1; mfma m0-3 x n2-3
#pragma unroll
    for (int n = 0; n < 2; ++n) { B23[n][0] = RDB(n + 2, pc0); B23[n][1] = RDB(n + 2, pc1); }
    if (t + 1 < NT) STAGE_A(nxt, 1, t + 1);
    QKV_BAR();
    __builtin_amdgcn_s_setprio(1);
#pragma unroll
    for (int m = 0; m < 4; ++m)
#pragma unroll
      for (int n = 0; n < 2; ++n) {
        QKV_MFMA(acc[m][n + 2], Af[m][0], B23[n][0]);
        QKV_MFMA(acc[m][n + 2], Af[m][1], B23[n][1]);
      }
    __builtin_amdgcn_s_setprio(0);
    QKV_BAR();
    // ---- phase 2: read A[4..7]; stage B(t+2).h0; mfma m4-7 x n0-1
#pragma unroll
    for (int m = 0; m < 4; ++m) { Af[m][0] = RDA(m + 4, pc0); Af[m][1] = RDA(m + 4, pc1); }
    if (t + 2 < NT) STAGE_B(cur, 0, t + 2);
    QKV_BAR();
    __builtin_amdgcn_s_setprio(1);
#pragma unroll
    for (int m = 0; m < 4; ++m)
#pragma unroll
      for (int n = 0; n < 2; ++n) {
        QKV_MFMA(acc[m + 4][n], Af[m][0], B01[n][0]);
        QKV_MFMA(acc[m + 4][n], Af[m][1], B01[n][1]);
      }
    __builtin_amdgcn_s_setprio(0);
    QKV_BAR();
    // ---- phase 3: no reads; stage B(t+2).h1; mfma m4-7 x n2-3
    if (t + 2 < NT) STAGE_B(cur, 1, t + 2);
    QKV_BAR();
    __builtin_amdgcn_s_setprio(1);
#pragma unroll
    for (int m = 0; m < 4; ++m)
#pragma unroll
      for (int n = 0; n < 2; ++n) {
        QKV_MFMA(acc[m + 4][n + 2], Af[m][0], B23[n][0]);
        QKV_MFMA(acc[m + 4][n + 2], Af[m][1], B23[n][1]);
      }
    __builtin_amdgcn_s_setprio(0);
    if (t < NT - 2) { asm volatile("s_waitcnt vmcnt(4)" ::: "memory"); }
    else            { asm volatile("s_waitcnt vmcnt(0)" ::: "memory"); }
    QKV_BAR();
  }
#undef RDA
#undef RDB

  // ---- epilogue ----
  if (sel == 2) {
    // V^T: out[(b,h,d,t)]; 4 consecutive t per acc quad -> 8B stores
#pragma unroll
    for (int ni = 0; ni < 4; ++ni) {
      const int n = n0 + wn * 64 + ni * 16 + lr;
      const float bv = bias[n];
      const int h = n >> 7, d = n & 127;
#pragma unroll
      for (int mi = 0; mi < 8; ++mi) {
        const int m = m0 + wm * 128 + mi * 16 + quad * 4;
        const int b = m >> 11, tt = m & 2047;
        unsigned short o4[4];
#pragma unroll
        for (int r = 0; r < 4; ++r) o4[r] = f2bf(acc[mi][ni][r] + bv);
        *(unsigned long long*)&Vo[(((size_t)(b * NH + h)) * HD + d) * Tn + tt] =
            *(const unsigned long long*)o4;
      }
    }
  } else {
    unsigned short* Out = (sel == 0) ? Qo : Ko;
#pragma unroll
    for (int ni = 0; ni < 4; ++ni) {
      const int n = n0 + wn * 64 + ni * 16 + lr;
      const float bv = bias[n];
      const int h = n >> 7, d = n & 127;
#pragma unroll
      for (int mi = 0; mi < 8; ++mi) {
#pragma unroll
        for (int r = 0; r < 4; ++r) {
          const int m = m0 + wm * 128 + mi * 16 + quad * 4 + r;
          const int b = m >> 11, tt = m & 2047;
          Out[(((size_t)(b * NH + h)) * Tn + tt) * HD + d] = f2bf(acc[mi][ni][r] + bv);
        }
      }
    }
  }
}

// ---------------- output projection GEMM (fp32 out) ----------------
// grid (16, 16, 2): x = n (fastest), y = m, z = batch. BK=32 + XOR swizzle.
__global__ __launch_bounds__(256) void gemm_proj_kernel(
    const unsigned short* __restrict__ Aall,  // (B, 2048, 2048) = O^T rows (h*128+d), cols t
    const unsigned short* __restrict__ W,     // Wp (N=C, K) bf16
    const float* __restrict__ bias,
    float* __restrict__ Y) {                  // (B, T, C) fp32
  __shared__ unsigned short As[128 * 32];
  __shared__ unsigned short Bs[128 * 32];
  const int tid = threadIdx.x;
  const int wave = tid >> 6, lane = tid & 63;
  const int wm = wave >> 1, wn = wave & 1;
  const int quad = lane >> 4, lr = lane & 15;

  const int m0 = blockIdx.y * 128, n0 = blockIdx.x * 128;
  const int bz = blockIdx.z;
  const unsigned short* A = Aall + (size_t)bz * Cn * Tn;

  f32x4 acc[4][4];
  const f32x4 zero4 = {0.f, 0.f, 0.f, 0.f};
#pragma unroll
  for (int i = 0; i < 4; ++i)
#pragma unroll
    for (int j = 0; j < 4; ++j) acc[i][j] = zero4;

  const int srow = tid >> 2;
  const int scol = (((tid & 3) ^ ((srow >> 1) & 3)) * 8);
  const unsigned short* Ag = A + (size_t)(m0 + srow) * Kdim + scol;
  const unsigned short* Bg = W + (size_t)(n0 + srow) * Kdim + scol;
  unsigned short* Al = &As[tid * 8];
  unsigned short* Bl = &Bs[tid * 8];
  const int fsw = (quad ^ ((lr >> 1) & 3)) * 8;

  for (int k0 = 0; k0 < Kdim; k0 += 32) {
    gload_lds16(Ag + k0, Al);
    gload_lds16(Ag + (size_t)64 * Kdim + k0, Al + 2048);
    gload_lds16(Bg + k0, Bl);
    gload_lds16(Bg + (size_t)64 * Kdim + k0, Bl + 2048);
    __syncthreads();
    short8 af[4], bf[4];
#pragma unroll
    for (int mi = 0; mi < 4; ++mi)
      af[mi] = *(const short8*)&As[(wm * 64 + mi * 16 + lr) * 32 + fsw];
#pragma unroll
    for (int ni = 0; ni < 4; ++ni)
      bf[ni] = *(const short8*)&Bs[(wn * 64 + ni * 16 + lr) * 32 + fsw];
#pragma unroll
    for (int mi = 0; mi < 4; ++mi)
#pragma unroll
      for (int ni = 0; ni < 4; ++ni)
        acc[mi][ni] = __builtin_amdgcn_mfma_f32_16x16x32_bf16(af[mi], bf[ni], acc[mi][ni], 0, 0, 0);
    __syncthreads();
  }

#pragma unroll
  for (int ni = 0; ni < 4; ++ni) {
    const int n = n0 + wn * 64 + ni * 16 + lr;
    const float bv = bias[n];
#pragma unroll
    for (int mi = 0; mi < 4; ++mi) {
#pragma unroll
      for (int r = 0; r < 4; ++r) {
        const int m = m0 + wm * 64 + mi * 16 + quad * 4 + r;
        Y[((size_t)bz * Tn + m) * Cn + n] = acc[mi][ni][r] + bv;
      }
    }
  }
}

// ---------------- flash attention (fixed-max softmax, paired q-tiles) ---
// Q,K: (BH, T, HD) bf16; V: (BH, HD, T) bf16 (written transposed by QKV).
// Output: O^T (B, H*HD, T) bf16 directly (epilogue transposes via Ps LDS).
// r2: T14 async-STAGE split — K/V for chunk c+1 loaded into registers
// right after the barrier that publishes chunk c, consumed (ds_write)
// at the next iteration top. Hides global latency under QK+softmax+PV.
__global__ __launch_bounds__(256, 1) void attn_kernel(
    const unsigned short* __restrict__ Q,
    const unsigned short* __restrict__ K,
    const unsigned short* __restrict__ V,
    unsigned short* __restrict__ Ot) {
  constexpr int KST = 136;
  constexpr int VST = 136;   // 144 x 136 (rows 128..143 = ones)
  constexpr int PST = 136;   // 128 x 136 (4 waves x 32 rows)
  __shared__ unsigned short Ks[128 * KST];
  __shared__ unsigned short Vs[144 * VST];
  __shared__ unsigned short Ps[128 * PST];

  const int tid = threadIdx.x;
  const int wave = tid >> 6, lane = tid & 63;
  const int quad = lane >> 4, lr = lane & 15;
  const int bh = blockIdx.y;
  const float SL = 0.08838834764831845f * 1.4426950408889634f;  // scale*log2(e)

  const unsigned short* Kp = K + (size_t)bh * Tn * HD;
  const unsigned short* Vp = V + (size_t)bh * HD * Tn;
  unsigned short* Pw = &Ps[wave * 32 * PST];

  for (int i = tid; i < 16 * VST; i += 256) Vs[128 * VST + i] = 0x3F80;

  // staging geometry (per thread): row r, 64-elem half cc
  const int r = tid >> 1;
  const int cc = (tid & 1) * 64;
  unsigned short* kl = &Ks[r * KST + cc];
  unsigned short* vl = &Vs[r * VST + cc];
  u32x4 kreg[8], vreg[8];

  const f32x4 zero4 = {0.f, 0.f, 0.f, 0.f};
#pragma unroll 1
  for (int half = 0; half < 2; ++half) {
    const int jt = half ? (15 - (int)blockIdx.x) : (int)blockIdx.x;
    const int q0 = jt * 128;

    const unsigned short* Qp = Q + ((size_t)bh * Tn + q0 + wave * 32) * HD;
    short8 qf[2][4];
#pragma unroll
    for (int mi = 0; mi < 2; ++mi)
#pragma unroll
      for (int ks = 0; ks < 4; ++ks)
        qf[mi][ks] = *(const short8*)&Qp[(mi * 16 + lr) * HD + ks * 32 + quad * 8];

    f32x4 oacc[2][9];
#pragma unroll
    for (int mi = 0; mi < 2; ++mi)
#pragma unroll
      for (int nd = 0; nd < 9; ++nd) oacc[mi][nd] = zero4;

    const int nch = q0 / 128 + 1;

    // prologue: chunk 0 -> registers
    {
      const unsigned short* kg = &Kp[(size_t)r * HD + cc];
      const unsigned short* vg = &Vp[(size_t)r * Tn + cc];
#pragma unroll
      for (int p = 0; p < 8; ++p) {
        kreg[p] = *(const u32x4*)(kg + p * 8);
        vreg[p] = *(const u32x4*)(vg + p * 8);
      }
    }

    for (int c = 0; c < nch; ++c) {
      const int k0 = c * 128;
      // publish chunk c (regs -> LDS)
#pragma unroll
      for (int p = 0; p < 8; ++p) {
        *(u32x4*)(kl + p * 8) = kreg[p];
        *(u32x4*)(vl + p * 8) = vreg[p];
      }
      __syncthreads();
      // issue chunk c+1 global loads now; consumed after next barrier
      if (c + 1 < nch) {
        const int k1 = k0 + 128;
        const unsigned short* kg = &Kp[(size_t)(k1 + r) * HD + cc];
        const unsigned short* vg = &Vp[(size_t)r * Tn + k1 + cc];
#pragma unroll
        for (int p = 0; p < 8; ++p) {
          kreg[p] = *(const u32x4*)(kg + p * 8);
          vreg[p] = *(const u32x4*)(vg + p * 8);
        }
      }

      f32x4 sa[2][8];
#pragma unroll
      for (int mi = 0; mi < 2; ++mi)
#pragma unroll
        for (int nt = 0; nt < 8; ++nt) sa[mi][nt] = zero4;
#pragma unroll
      for (int nt = 0; nt < 8; ++nt) {
        short8 kf[4];
#pragma unroll
        for (int ks = 0; ks < 4; ++ks)
          kf[ks] = *(const short8*)&Ks[(nt * 16 + lr) * KST + ks * 32 + quad * 8];
#pragma unroll
        for (int mi = 0; mi < 2; ++mi)
#pragma unroll
          for (int ks = 0; ks < 4; ++ks)
            sa[mi][nt] = __builtin_amdgcn_mfma_f32_16x16x32_bf16(qf[mi][ks], kf[ks], sa[mi][nt], 0, 0, 0);
      }

      if (k0 == q0) {
#pragma unroll
        for (int mi = 0; mi < 2; ++mi)
#pragma unroll
          for (int nt = 0; nt < 8; ++nt)
#pragma unroll
            for (int r2 = 0; r2 < 4; ++r2) {
              const int qg = q0 + wave * 32 + mi * 16 + quad * 4 + r2;
              const int kg = k0 + nt * 16 + lr;
              if (kg > qg) sa[mi][nt][r2] = -3.0e38f;
            }
      }

#pragma unroll
      for (int mi = 0; mi < 2; ++mi)
#pragma unroll
        for (int nt = 0; nt < 8; ++nt)
#pragma unroll
          for (int r2 = 0; r2 < 4; ++r2) {
            const float p = __builtin_amdgcn_exp2f(sa[mi][nt][r2] * SL);
            Pw[(mi * 16 + quad * 4 + r2) * PST + nt * 16 + lr] = f2bf(p);
          }

#pragma unroll
      for (int kt = 0; kt < 4; ++kt) {
        short8 pf[2];
#pragma unroll
        for (int mi = 0; mi < 2; ++mi)
          pf[mi] = *(const short8*)&Pw[(mi * 16 + lr) * PST + kt * 32 + quad * 8];
#pragma unroll
        for (int nd = 0; nd < 9; ++nd) {
          short8 vf = *(const short8*)&Vs[(nd * 16 + lr) * VST + kt * 32 + quad * 8];
#pragma unroll
          for (int mi = 0; mi < 2; ++mi)
            oacc[mi][nd] = __builtin_amdgcn_mfma_f32_16x16x32_bf16(pf[mi], vf, oacc[mi][nd], 0, 0, 0);
        }
      }
      __syncthreads();
    }

    // epilogue: normalize, stage into Ps (t-major), write O^T coalesced
#pragma unroll
    for (int mi = 0; mi < 2; ++mi)
#pragma unroll
      for (int r2 = 0; r2 < 4; ++r2) {
        const float rl = 1.0f / oacc[mi][8][r2];
        const int tl = wave * 32 + mi * 16 + quad * 4 + r2;
#pragma unroll
        for (int nd = 0; nd < 8; ++nd)
          Ps[tl * PST + nd * 16 + lr] = f2bf(oacc[mi][nd][r2] * rl);
      }
    __syncthreads();
    {
      unsigned short* Od = Ot + (size_t)bh * HD * Tn + q0;  // row = d, stride Tn
#pragma unroll
      for (int p = 0; p < 8; ++p) {
        const int d = p * 16 + (tid >> 4);
        const int t8 = (tid & 15) * 8;
        alignas(16) unsigned short v[8];
#pragma unroll
        for (int j = 0; j < 8; ++j) v[j] = Ps[(t8 + j) * PST + d];
        *(u32x4*)&Od[(size_t)d * Tn + t8] = *(const u32x4*)v;
      }
    }
    __syncthreads();
  }
}

extern "C" void kernel_launch(void* const* d_in, const int* in_sizes, int n_in,
                              void* d_out, int out_size, void* d_ws, size_t ws_size,
                              hipStream_t stream) {
  const float* x  = (const float*)d_in[0];
  const float* Wq = (const float*)d_in[1];
  const float* bq = (const float*)d_in[2];
  const float* Wk = (const float*)d_in[3];
  const float* bk = (const float*)d_in[4];
  const float* Wv = (const float*)d_in[5];
  const float* bv = (const float*)d_in[6];
  const float* Wp = (const float*)d_in[7];
  const float* bp = (const float*)d_in[8];
  float* out = (float*)d_out;

  char* ws = (char*)d_ws;
  const size_t MB = 1ull << 20;
  unsigned short* Xbf = (unsigned short*)(ws);             // 16MB
  unsigned short* Wqb = (unsigned short*)(ws + 16 * MB);   // 8MB each
  unsigned short* Wkb = (unsigned short*)(ws + 24 * MB);
  unsigned short* Wvb = (unsigned short*)(ws + 32 * MB);
  unsigned short* Wpb = (unsigned short*)(ws + 40 * MB);
  unsigned short* Qb  = (unsigned short*)(ws + 48 * MB);   // 16MB
  unsigned short* Kb  = (unsigned short*)(ws + 64 * MB);   // 16MB
  unsigned short* Vtb = (unsigned short*)(ws + 80 * MB);   // 16MB (B,H,D,T)
  unsigned short* Otb = (unsigned short*)(ws + 96 * MB);   // 16MB (B,H*D,T)

  cast_bf16_kernel<<<dim3(1024), dim3(256), 0, stream>>>(x, Xbf, Bn * Tn * Cn);
  cast4_kernel<<<dim3(512, 4), dim3(256), 0, stream>>>(
      Wq, Wk, Wv, Wp, Wqb, Wkb, Wvb, Wpb, Cn * Cn);

  gemm_qkv_8ph_kernel<<<dim3(24, 16), dim3(512), 0, stream>>>(
      Xbf, Wqb, Wkb, Wvb, bq, bk, bv, Qb, Kb, Vtb);

  attn_kernel<<<dim3(8, Bn * NH), dim3(256), 0, stream>>>(Qb, Kb, Vtb, Otb);

  gemm_proj_kernel<<<dim3(16, 16, 2), dim3(256), 0, stream>>>(Otb, Wpb, bp, out);
}

// Round 4
// 410.534 us; speedup vs baseline: 1.0748x; 1.0155x over previous
//
#include <hip/hip_runtime.h>
#include <stdint.h>

#define DEVI __device__ __forceinline__

typedef __attribute__((ext_vector_type(8))) short short8;
typedef __attribute__((ext_vector_type(4))) float f32x4;
typedef __attribute__((ext_vector_type(4))) unsigned int u32x4;

static constexpr int Bn = 2;
static constexpr int Tn = 2048;
static constexpr int Cn = 2048;
static constexpr int NH = 16;
static constexpr int HD = 128;
static constexpr int Kdim = 2048;

DEVI unsigned short f2bf(float f) {
  union { float f; unsigned u; } v; v.f = f;
  return (unsigned short)((v.u + 0x7FFFu + ((v.u >> 16) & 1u)) >> 16);
}

DEVI void gload_lds16(const void* g, void* l) {
  __builtin_amdgcn_global_load_lds(
      (const __attribute__((address_space(1))) void*)g,
      (__attribute__((address_space(3))) void*)l, 16, 0, 0);
}

// ---------------- cast fp32 -> bf16 (RNE) ----------------
__global__ __launch_bounds__(256) void cast_bf16_kernel(
    const float* __restrict__ src, unsigned short* __restrict__ dst, int n) {
  int idx = (blockIdx.x * blockDim.x + threadIdx.x) * 4;
  const int stride = gridDim.x * blockDim.x * 4;
  for (; idx < n; idx += stride) {
    f32x4 f = *(const f32x4*)(src + idx);
    unsigned short o[4];
    o[0] = f2bf(f[0]); o[1] = f2bf(f[1]); o[2] = f2bf(f[2]); o[3] = f2bf(f[3]);
    *(unsigned long long*)(dst + idx) = *(const unsigned long long*)o;
  }
}

__global__ __launch_bounds__(256) void cast4_kernel(
    const float* __restrict__ s0, const float* __restrict__ s1,
    const float* __restrict__ s2, const float* __restrict__ s3,
    unsigned short* __restrict__ d0, unsigned short* __restrict__ d1,
    unsigned short* __restrict__ d2, unsigned short* __restrict__ d3, int n) {
  const int w = blockIdx.y;
  const float* src = (w == 0) ? s0 : (w == 1) ? s1 : (w == 2) ? s2 : s3;
  unsigned short* dst = (w == 0) ? d0 : (w == 1) ? d1 : (w == 2) ? d2 : d3;
  int idx = (blockIdx.x * blockDim.x + threadIdx.x) * 4;
  const int stride = gridDim.x * blockDim.x * 4;
  for (; idx < n; idx += stride) {
    f32x4 f = *(const f32x4*)(src + idx);
    unsigned short o[4];
    o[0] = f2bf(f[0]); o[1] = f2bf(f[1]); o[2] = f2bf(f[2]); o[3] = f2bf(f[3]);
    *(unsigned long long*)(dst + idx) = *(const unsigned long long*)o;
  }
}

// ============ 256x128-tile 8-wave BK=64 pipelined GEMM (shared shape) =====
// 8 waves as 2M x 4N, wave-tile 128x32 (8 m-frags x 2 n-frags), BK=64.
// LDS 96 KB: 2 bufs x (A 256x64 + B 128x64). 2 phases per K-tile, 16 MFMA
// each (same barrier:MFMA ratio as the proven 4-phase 256^2 schedule).
// Staging: ph0 stages A(t+1).h0 -> nxt; ph1 stages A(t+1).h1 -> nxt and
// B(t+2) -> cur (safe: all waves' B(t) reads complete at ph0's closing
// barrier). Boundary vmcnt(2) keeps B(t+2)'s 2 loads in flight.
// Chunk-XOR swizzle: phys 16B chunk = logical ^ (row&7), row&7 == lr&7.
// Grid geometry: QKV 16x48 = 768 blocks = 3 exact rounds @1 block/CU;
// proj 8x16x2 = 256 blocks = 1 exact round. (256^2 gave 384 blocks = 1.5
// rounds -> a full half-idle round; this retile removes the tail.)
#define G_BAR() __builtin_amdgcn_s_barrier()
#define G_MFMA(d, a, b) d = __builtin_amdgcn_mfma_f32_16x16x32_bf16(a, b, d, 0, 0, 0)

#define GEMM_CORE_256x128(Asrc_, Bsrc_)                                          \
  f32x4 acc[8][2];                                                               \
  const f32x4 zero4 = {0.f, 0.f, 0.f, 0.f};                                      \
  _Pragma("unroll") for (int i = 0; i < 8; ++i)                                  \
      _Pragma("unroll") for (int j = 0; j < 2; ++j) acc[i][j] = zero4;           \
  const int srow = tid >> 3;                                                     \
  const int schunk = (tid & 7) ^ (srow & 7);                                     \
  const unsigned short* Asrc = (Asrc_) + (size_t)srow * Kdim + schunk * 8;       \
  const unsigned short* Bsrc = (Bsrc_) + (size_t)srow * Kdim + schunk * 8;       \
  auto STAGE_A = [&](int buf, int h, int t) {                                    \
    unsigned short* d = &L[buf][h * 8192 + tid * 8];                             \
    const unsigned short* s = Asrc + (size_t)(h * 128) * Kdim + t * 64;          \
    gload_lds16(s, d);                                                           \
    gload_lds16(s + (size_t)64 * Kdim, d + 4096);                                \
  };                                                                             \
  auto STAGE_B = [&](int buf, int t) {                                           \
    unsigned short* d = &L[buf][16384 + tid * 8];                                \
    const unsigned short* s = Bsrc + t * 64;                                     \
    gload_lds16(s, d);                                                           \
    gload_lds16(s + (size_t)64 * Kdim, d + 4096);                                \
  };                                                                             \
  const int pc0 = (quad) ^ (lr & 7);                                             \
  const int pc1 = (4 + quad) ^ (lr & 7);                                         \
  const int aoff = (wm * 128 + lr) * 64;                                         \
  const int boff = 16384 + (wn * 32 + lr) * 64;                                  \
  STAGE_A(0, 0, 0); STAGE_A(0, 1, 0);                                            \
  STAGE_B(0, 0);                                                                 \
  STAGE_B(1, 1);                                                                 \
  asm volatile("s_waitcnt vmcnt(2)" ::: "memory");                               \
  G_BAR();                                                                       \
  short8 Af[4][2], Bf[2][2];                                                     \
  for (int t = 0; t < NT; ++t) {                                                 \
    const int cur = t & 1, nxt = cur ^ 1;                                        \
    _Pragma("unroll") for (int m = 0; m < 4; ++m) {                              \
      Af[m][0] = *(const short8*)&L[cur][aoff + m * 1024 + pc0 * 8];             \
      Af[m][1] = *(const short8*)&L[cur][aoff + m * 1024 + pc1 * 8];             \
    }                                                                            \
    _Pragma("unroll") for (int n = 0; n < 2; ++n) {                              \
      Bf[n][0] = *(const short8*)&L[cur][boff + n * 1024 + pc0 * 8];             \
      Bf[n][1] = *(const short8*)&L[cur][boff + n * 1024 + pc1 * 8];             \
    }                                                                            \
    if (t + 1 < NT) STAGE_A(nxt, 0, t + 1);                                      \
    G_BAR();                                                                     \
    __builtin_amdgcn_s_setprio(1);                                               \
    _Pragma("unroll") for (int m = 0; m < 4; ++m)                                \
        _Pragma("unroll") for (int n = 0; n < 2; ++n) {                          \
      G_MFMA(acc[m][n], Af[m][0], Bf[n][0]);                                     \
      G_MFMA(acc[m][n], Af[m][1], Bf[n][1]);                                     \
    }                                                                            \
    __builtin_amdgcn_s_setprio(0);                                               \
    G_BAR();                                                                     \
    _Pragma("unroll") for (int m = 0; m < 4; ++m) {                              \
      Af[m][0] = *(const short8*)&L[cur][aoff + (m + 4) * 1024 + pc0 * 8];       \
      Af[m][1] = *(const short8*)&L[cur][aoff + (m + 4) * 1024 + pc1 * 8];       \
    }                                                                            \
    if (t + 1 < NT) STAGE_A(nxt, 1, t + 1);                                      \
    if (t + 2 < NT) STAGE_B(cur, t + 2);                                         \
    G_BAR();                                                                     \
    __builtin_amdgcn_s_setprio(1);                                               \
    _Pragma("unroll") for (int m = 0; m < 4; ++m)                                \
        _Pragma("unroll") for (int n = 0; n < 2; ++n) {                          \
      G_MFMA(acc[m + 4][n], Af[m][0], Bf[n][0]);                                 \
      G_MFMA(acc[m + 4][n], Af[m][1], Bf[n][1]);                                 \
    }                                                                            \
    __builtin_amdgcn_s_setprio(0);                                               \
    if (t < NT - 2) { asm volatile("s_waitcnt vmcnt(2)" ::: "memory"); }         \
    else            { asm volatile("s_waitcnt vmcnt(0)" ::: "memory"); }         \
    G_BAR();                                                                     \
  }

// ---------------- fused QKV projection GEMM ----------------
// grid (48, 16): bx: 16 n-blocks per matrix x 3 matrices; by: 16 m-blocks.
// Q/K out: (B,H,T,D) bf16 scattered; V out: (B,H,D,T) bf16 (pre-transposed).
__global__ __launch_bounds__(512, 2) void gemm_qkv_256x128_kernel(
    const unsigned short* __restrict__ X,
    const unsigned short* __restrict__ Wq_, const unsigned short* __restrict__ Wk_,
    const unsigned short* __restrict__ Wv_,
    const float* __restrict__ bq_, const float* __restrict__ bk_, const float* __restrict__ bv_,
    unsigned short* __restrict__ Qo, unsigned short* __restrict__ Ko,
    unsigned short* __restrict__ Vo) {
  constexpr int NT = Kdim / 64;  // 32 K-tiles
  __shared__ unsigned short L[2][24576];  // [buf][A 16384 | B 8192], 96 KB

  const int tid = threadIdx.x;
  const int wave = tid >> 6, lane = tid & 63;
  const int wm = wave >> 2, wn = wave & 3;   // 2M x 4N
  const int quad = lane >> 4, lr = lane & 15;

  // XCD-bijective swizzle: 768 = 8 XCDs x 96 contiguous (n-fastest)
  const int flat = (int)blockIdx.x + 48 * (int)blockIdx.y;
  const int swz = (flat & 7) * 96 + (flat >> 3);
  const int bx = swz % 48, by = swz / 48;
  const int sel = bx >> 4;                   // 0=Q 1=K 2=V
  const int nw0 = (bx & 15) * 128;           // n within selected matrix
  const int m0 = by * 256;
  const unsigned short* W = (sel == 0) ? Wq_ : (sel == 1) ? Wk_ : Wv_;
  const float* bias = (sel == 0) ? bq_ : (sel == 1) ? bk_ : bv_;

  GEMM_CORE_256x128(X + (size_t)m0 * Kdim, W + (size_t)nw0 * Kdim)

  // ---- epilogue ----
  if (sel == 2) {
    // V^T: out[(b,h,d,t)]; 4 consecutive t per acc quad -> 8B stores
#pragma unroll
    for (int ni = 0; ni < 2; ++ni) {
      const int n = nw0 + wn * 32 + ni * 16 + lr;
      const float bv = bias[n];
      const int h = n >> 7, d = n & 127;
#pragma unroll
      for (int mi = 0; mi < 8; ++mi) {
        const int m = m0 + wm * 128 + mi * 16 + quad * 4;
        const int b = m >> 11, tt = m & 2047;
        unsigned short o4[4];
#pragma unroll
        for (int r = 0; r < 4; ++r) o4[r] = f2bf(acc[mi][ni][r] + bv);
        *(unsigned long long*)&Vo[(((size_t)(b * NH + h)) * HD + d) * Tn + tt] =
            *(const unsigned long long*)o4;
      }
    }
  } else {
    unsigned short* Out = (sel == 0) ? Qo : Ko;
#pragma unroll
    for (int ni = 0; ni < 2; ++ni) {
      const int n = nw0 + wn * 32 + ni * 16 + lr;
      const float bv = bias[n];
      const int h = n >> 7, d = n & 127;
#pragma unroll
      for (int mi = 0; mi < 8; ++mi) {
#pragma unroll
        for (int r = 0; r < 4; ++r) {
          const int m = m0 + wm * 128 + mi * 16 + quad * 4 + r;
          const int b = m >> 11, tt = m & 2047;
          Out[(((size_t)(b * NH + h)) * Tn + tt) * HD + d] = f2bf(acc[mi][ni][r] + bv);
        }
      }
    }
  }
}

// ---------------- output projection GEMM (fp32 out) ----------------
// grid (16, 8, 2): x = n (fastest), y = m, z = batch. 256 blocks = 1 round.
__global__ __launch_bounds__(512, 2) void gemm_proj_256x128_kernel(
    const unsigned short* __restrict__ Aall,  // (B, 2048, 2048)
    const unsigned short* __restrict__ Wp_,   // (N=C, K) bf16
    const float* __restrict__ bias,
    float* __restrict__ Y) {                  // (B, 2048, 2048) fp32
  constexpr int NT = Kdim / 64;
  __shared__ unsigned short L[2][24576];

  const int tid = threadIdx.x;
  const int wave = tid >> 6, lane = tid & 63;
  const int wm = wave >> 2, wn = wave & 3;
  const int quad = lane >> 4, lr = lane & 15;

  // per-z-slice XCD swizzle: 128 = 8 x 16
  const int flat = (int)blockIdx.x + 16 * (int)blockIdx.y;
  const int swz = (flat & 7) * 16 + (flat >> 3);
  const int bx = swz % 16, by = swz / 16;
  const int m0 = by * 256, n0 = bx * 128;
  const int bz = blockIdx.z;
  const unsigned short* A = Aall + (size_t)bz * Cn * Tn;

  GEMM_CORE_256x128(A + (size_t)m0 * Kdim, Wp_ + (size_t)n0 * Kdim)

#pragma unroll
  for (int ni = 0; ni < 2; ++ni) {
    const int n = n0 + wn * 32 + ni * 16 + lr;
    const float bv = bias[n];
#pragma unroll
    for (int mi = 0; mi < 8; ++mi) {
#pragma unroll
      for (int r = 0; r < 4; ++r) {
        const int m = m0 + wm * 128 + mi * 16 + quad * 4 + r;
        Y[((size_t)bz * Tn + m) * Cn + n] = acc[mi][ni][r] + bv;
      }
    }
  }
}

// ---------------- flash attention (fixed-max softmax, paired q-tiles) ---
// Q,K: (BH, T, HD) bf16; V: (BH, HD, T) bf16 (written transposed by QKV).
// Output: O^T (B, H*HD, T) bf16 directly (epilogue transposes via Ps LDS).
// T14 async-STAGE split: chunk c+1 K/V loaded to regs right after the
// barrier publishing chunk c; consumed (ds_write) at next iteration top.
__global__ __launch_bounds__(256, 1) void attn_kernel(
    const unsigned short* __restrict__ Q,
    const unsigned short* __restrict__ K,
    const unsigned short* __restrict__ V,
    unsigned short* __restrict__ Ot) {
  constexpr int KST = 136;
  constexpr int VST = 136;   // 144 x 136 (rows 128..143 = ones)
  constexpr int PST = 136;   // 128 x 136 (4 waves x 32 rows)
  __shared__ unsigned short Ks[128 * KST];
  __shared__ unsigned short Vs[144 * VST];
  __shared__ unsigned short Ps[128 * PST];

  const int tid = threadIdx.x;
  const int wave = tid >> 6, lane = tid & 63;
  const int quad = lane >> 4, lr = lane & 15;
  const int bh = blockIdx.y;
  const float SL = 0.08838834764831845f * 1.4426950408889634f;  // scale*log2(e)

  const unsigned short* Kp = K + (size_t)bh * Tn * HD;
  const unsigned short* Vp = V + (size_t)bh * HD * Tn;
  unsigned short* Pw = &Ps[wave * 32 * PST];

  for (int i = tid; i < 16 * VST; i += 256) Vs[128 * VST + i] = 0x3F80;

  const int r = tid >> 1;
  const int cc = (tid & 1) * 64;
  unsigned short* kl = &Ks[r * KST + cc];
  unsigned short* vl = &Vs[r * VST + cc];
  u32x4 kreg[8], vreg[8];

  const f32x4 zero4 = {0.f, 0.f, 0.f, 0.f};
#pragma unroll 1
  for (int half = 0; half < 2; ++half) {
    const int jt = half ? (15 - (int)blockIdx.x) : (int)blockIdx.x;
    const int q0 = jt * 128;

    const unsigned short* Qp = Q + ((size_t)bh * Tn + q0 + wave * 32) * HD;
    short8 qf[2][4];
#pragma unroll
    for (int mi = 0; mi < 2; ++mi)
#pragma unroll
      for (int ks = 0; ks < 4; ++ks)
        qf[mi][ks] = *(const short8*)&Qp[(mi * 16 + lr) * HD + ks * 32 + quad * 8];

    f32x4 oacc[2][9];
#pragma unroll
    for (int mi = 0; mi < 2; ++mi)
#pragma unroll
      for (int nd = 0; nd < 9; ++nd) oacc[mi][nd] = zero4;

    const int nch = q0 / 128 + 1;

    {
      const unsigned short* kg = &Kp[(size_t)r * HD + cc];
      const unsigned short* vg = &Vp[(size_t)r * Tn + cc];
#pragma unroll
      for (int p = 0; p < 8; ++p) {
        kreg[p] = *(const u32x4*)(kg + p * 8);
        vreg[p] = *(const u32x4*)(vg + p * 8);
      }
    }

    for (int c = 0; c < nch; ++c) {
      const int k0 = c * 128;
#pragma unroll
      for (int p = 0; p < 8; ++p) {
        *(u32x4*)(kl + p * 8) = kreg[p];
        *(u32x4*)(vl + p * 8) = vreg[p];
      }
      __syncthreads();
      if (c + 1 < nch) {
        const int k1 = k0 + 128;
        const unsigned short* kg = &Kp[(size_t)(k1 + r) * HD + cc];
        const unsigned short* vg = &Vp[(size_t)r * Tn + k1 + cc];
#pragma unroll
        for (int p = 0; p < 8; ++p) {
          kreg[p] = *(const u32x4*)(kg + p * 8);
          vreg[p] = *(const u32x4*)(vg + p * 8);
        }
      }

      f32x4 sa[2][8];
#pragma unroll
      for (int mi = 0; mi < 2; ++mi)
#pragma unroll
        for (int nt = 0; nt < 8; ++nt) sa[mi][nt] = zero4;
#pragma unroll
      for (int nt = 0; nt < 8; ++nt) {
        short8 kf[4];
#pragma unroll
        for (int ks = 0; ks < 4; ++ks)
          kf[ks] = *(const short8*)&Ks[(nt * 16 + lr) * KST + ks * 32 + quad * 8];
#pragma unroll
        for (int mi = 0; mi < 2; ++mi)
#pragma unroll
          for (int ks = 0; ks < 4; ++ks)
            sa[mi][nt] = __builtin_amdgcn_mfma_f32_16x16x32_bf16(qf[mi][ks], kf[ks], sa[mi][nt], 0, 0, 0);
      }

      if (k0 == q0) {
#pragma unroll
        for (int mi = 0; mi < 2; ++mi)
#pragma unroll
          for (int nt = 0; nt < 8; ++nt)
#pragma unroll
            for (int r2 = 0; r2 < 4; ++r2) {
              const int qg = q0 + wave * 32 + mi * 16 + quad * 4 + r2;
              const int kg = k0 + nt * 16 + lr;
              if (kg > qg) sa[mi][nt][r2] = -3.0e38f;
            }
      }

#pragma unroll
      for (int mi = 0; mi < 2; ++mi)
#pragma unroll
        for (int nt = 0; nt < 8; ++nt)
#pragma unroll
          for (int r2 = 0; r2 < 4; ++r2) {
            const float p = __builtin_amdgcn_exp2f(sa[mi][nt][r2] * SL);
            Pw[(mi * 16 + quad * 4 + r2) * PST + nt * 16 + lr] = f2bf(p);
          }

#pragma unroll
      for (int kt = 0; kt < 4; ++kt) {
        short8 pf[2];
#pragma unroll
        for (int mi = 0; mi < 2; ++mi)
          pf[mi] = *(const short8*)&Pw[(mi * 16 + lr) * PST + kt * 32 + quad * 8];
#pragma unroll
        for (int nd = 0; nd < 9; ++nd) {
          short8 vf = *(const short8*)&Vs[(nd * 16 + lr) * VST + kt * 32 + quad * 8];
#pragma unroll
          for (int mi = 0; mi < 2; ++mi)
            oacc[mi][nd] = __builtin_amdgcn_mfma_f32_16x16x32_bf16(pf[mi], vf, oacc[mi][nd], 0, 0, 0);
        }
      }
      __syncthreads();
    }

    // epilogue: normalize, stage into Ps (t-major), write O^T coalesced
#pragma unroll
    for (int mi = 0; mi < 2; ++mi)
#pragma unroll
      for (int r2 = 0; r2 < 4; ++r2) {
        const float rl = 1.0f / oacc[mi][8][r2];
        const int tl = wave * 32 + mi * 16 + quad * 4 + r2;
#pragma unroll
        for (int nd = 0; nd < 8; ++nd)
          Ps[tl * PST + nd * 16 + lr] = f2bf(oacc[mi][nd][r2] * rl);
      }
    __syncthreads();
    {
      unsigned short* Od = Ot + (size_t)bh * HD * Tn + q0;  // row = d, stride Tn
#pragma unroll
      for (int p = 0; p < 8; ++p) {
        const int d = p * 16 + (tid >> 4);
        const int t8 = (tid & 15) * 8;
        alignas(16) unsigned short v[8];
#pragma unroll
        for (int j = 0; j < 8; ++j) v[j] = Ps[(t8 + j) * PST + d];
        *(u32x4*)&Od[(size_t)d * Tn + t8] = *(const u32x4*)v;
      }
    }
    __syncthreads();
  }
}

extern "C" void kernel_launch(void* const* d_in, const int* in_sizes, int n_in,
                              void* d_out, int out_size, void* d_ws, size_t ws_size,
                              hipStream_t stream) {
  const float* x  = (const float*)d_in[0];
  const float* Wq = (const float*)d_in[1];
  const float* bq = (const float*)d_in[2];
  const float* Wk = (const float*)d_in[3];
  const float* bk = (const float*)d_in[4];
  const float* Wv = (const float*)d_in[5];
  const float* bv = (const float*)d_in[6];
  const float* Wp = (const float*)d_in[7];
  const float* bp = (const float*)d_in[8];
  float* out = (float*)d_out;

  char* ws = (char*)d_ws;
  const size_t MB = 1ull << 20;
  unsigned short* Xbf = (unsigned short*)(ws);             // 16MB
  unsigned short* Wqb = (unsigned short*)(ws + 16 * MB);   // 8MB each
  unsigned short* Wkb = (unsigned short*)(ws + 24 * MB);
  unsigned short* Wvb = (unsigned short*)(ws + 32 * MB);
  unsigned short* Wpb = (unsigned short*)(ws + 40 * MB);
  unsigned short* Qb  = (unsigned short*)(ws + 48 * MB);   // 16MB
  unsigned short* Kb  = (unsigned short*)(ws + 64 * MB);   // 16MB
  unsigned short* Vtb = (unsigned short*)(ws + 80 * MB);   // 16MB (B,H,D,T)
  unsigned short* Otb = (unsigned short*)(ws + 96 * MB);   // 16MB (B,H*D,T)

  cast_bf16_kernel<<<dim3(1024), dim3(256), 0, stream>>>(x, Xbf, Bn * Tn * Cn);
  cast4_kernel<<<dim3(512, 4), dim3(256), 0, stream>>>(
      Wq, Wk, Wv, Wp, Wqb, Wkb, Wvb, Wpb, Cn * Cn);

  gemm_qkv_256x128_kernel<<<dim3(48, 16), dim3(512), 0, stream>>>(
      Xbf, Wqb, Wkb, Wvb, bq, bk, bv, Qb, Kb, Vtb);

  attn_kernel<<<dim3(8, Bn * NH), dim3(256), 0, stream>>>(Qb, Kb, Vtb, Otb);

  gemm_proj_256x128_kernel<<<dim3(16, 8, 2), dim3(512), 0, stream>>>(
      Otb, Wpb, bp, out);
}

// Round 5
// 395.949 us; speedup vs baseline: 1.1144x; 1.0368x over previous
//
#include <hip/hip_runtime.h>
#include <stdint.h>

#define DEVI __device__ __forceinline__

typedef __attribute__((ext_vector_type(8))) short short8;
typedef __attribute__((ext_vector_type(4))) float f32x4;
typedef __attribute__((ext_vector_type(4))) unsigned int u32x4;

static constexpr int Bn = 2;
static constexpr int Tn = 2048;
static constexpr int Cn = 2048;
static constexpr int NH = 16;
static constexpr int HD = 128;
static constexpr int Kdim = 2048;

DEVI unsigned short f2bf(float f) {
  union { float f; unsigned u; } v; v.f = f;
  return (unsigned short)((v.u + 0x7FFFu + ((v.u >> 16) & 1u)) >> 16);
}

DEVI void gload_lds16(const void* g, void* l) {
  __builtin_amdgcn_global_load_lds(
      (const __attribute__((address_space(1))) void*)g,
      (__attribute__((address_space(3))) void*)l, 16, 0, 0);
}

// ---------------- cast fp32 -> bf16 (RNE) ----------------
__global__ __launch_bounds__(256) void cast_bf16_kernel(
    const float* __restrict__ src, unsigned short* __restrict__ dst, int n) {
  int idx = (blockIdx.x * blockDim.x + threadIdx.x) * 4;
  const int stride = gridDim.x * blockDim.x * 4;
  for (; idx < n; idx += stride) {
    f32x4 f = *(const f32x4*)(src + idx);
    unsigned short o[4];
    o[0] = f2bf(f[0]); o[1] = f2bf(f[1]); o[2] = f2bf(f[2]); o[3] = f2bf(f[3]);
    *(unsigned long long*)(dst + idx) = *(const unsigned long long*)o;
  }
}

__global__ __launch_bounds__(256) void cast4_kernel(
    const float* __restrict__ s0, const float* __restrict__ s1,
    const float* __restrict__ s2, const float* __restrict__ s3,
    unsigned short* __restrict__ d0, unsigned short* __restrict__ d1,
    unsigned short* __restrict__ d2, unsigned short* __restrict__ d3, int n) {
  const int w = blockIdx.y;
  const float* src = (w == 0) ? s0 : (w == 1) ? s1 : (w == 2) ? s2 : s3;
  unsigned short* dst = (w == 0) ? d0 : (w == 1) ? d1 : (w == 2) ? d2 : d3;
  int idx = (blockIdx.x * blockDim.x + threadIdx.x) * 4;
  const int stride = gridDim.x * blockDim.x * 4;
  for (; idx < n; idx += stride) {
    f32x4 f = *(const f32x4*)(src + idx);
    unsigned short o[4];
    o[0] = f2bf(f[0]); o[1] = f2bf(f[1]); o[2] = f2bf(f[2]); o[3] = f2bf(f[3]);
    *(unsigned long long*)(dst + idx) = *(const unsigned long long*)o;
  }
}

#define G_BAR() __builtin_amdgcn_s_barrier()
#define G_MFMA(d, a, b) d = __builtin_amdgcn_mfma_f32_16x16x32_bf16(a, b, d, 0, 0, 0)

// ---------------- fused QKV projection GEMM: 256x192 over W3 ----------------
// W3 = [Wq;Wk;Wv] contiguous (6144, 2048). Tile 256x192 -> grid 16x32 = 512
// blocks = EXACTLY 2 dispatch rounds @1 block/CU (r4 lesson: packing and
// wave-N fatness must come together; 256x128 had exact packing but ratio
// 1.6 ds_read_b128:MFMA made LDS co-critical -> 37% in-round).
// 8 waves 2M x 4N, wave-tile 128x48 (8 m-frags x 3 n-frags), BK=64.
// LDS 112 KB: 2 bufs x (A 256x64 + B 192x64). 2 phases/K-tile, 24 MFMA
// each (12 MFMA per barrier). ph0 reads A[0..3]+B[0..2] (14 b128), stages
// A(t+1) (4 loads); ph1 reads A[4..7] (8 b128), stages B(t+2) (3 loads,
// safe: B(t) reads done at ph0's post-MFMA barrier). Boundary vmcnt(3)
// keeps exactly B(t+2) in flight. Chunk-XOR swizzle: phys 16B chunk =
// logical ^ (row&7); row&7 == lr&7 for all frag rows (bases multiple of 16).
// Tiles straddle Q/K/V boundaries; each 16-wide n-frag stays within one
// head and one matrix (16|128|2048), so epilogue routes per-frag.
__global__ __launch_bounds__(512, 2) void gemm_qkv_256x192_kernel(
    const unsigned short* __restrict__ X,
    const unsigned short* __restrict__ W3,
    const float* __restrict__ bq_, const float* __restrict__ bk_, const float* __restrict__ bv_,
    unsigned short* __restrict__ Qo, unsigned short* __restrict__ Ko,
    unsigned short* __restrict__ Vo) {
  constexpr int NT = Kdim / 64;  // 32 K-tiles
  __shared__ unsigned short L[2][28672];  // [A 16384 | B 12288] shorts

  const int tid = threadIdx.x;
  const int wave = tid >> 6, lane = tid & 63;
  const int wm = wave >> 2, wn = wave & 3;   // 2M x 4N
  const int quad = lane >> 4, lr = lane & 15;

  // XCD-bijective swizzle: 512 = 8 XCDs x 64 contiguous (n-fastest)
  const int flat = (int)blockIdx.x + 32 * (int)blockIdx.y;
  const int swz = (flat & 7) * 64 + (flat >> 3);
  const int bx = swz & 31, by = swz >> 5;
  const int n0 = bx * 192;                   // global n in [0, 6144)
  const int m0 = by * 256;

  f32x4 acc[8][3];
  const f32x4 zero4 = {0.f, 0.f, 0.f, 0.f};
#pragma unroll
  for (int i = 0; i < 8; ++i)
#pragma unroll
    for (int j = 0; j < 3; ++j) acc[i][j] = zero4;

  const int srow = tid >> 3;                 // 0..63
  const int schunk = (tid & 7) ^ (srow & 7);
  const unsigned short* Asrc = X + (size_t)(m0 + srow) * Kdim + schunk * 8;
  const unsigned short* Bsrc = W3 + (size_t)(n0 + srow) * Kdim + schunk * 8;

  auto STAGE_A = [&](int buf, int t) {       // 4 loads: rows 0..255
    unsigned short* d = &L[buf][tid * 8];
    const unsigned short* s = Asrc + t * 64;
#pragma unroll
    for (int h = 0; h < 4; ++h)
      gload_lds16(s + (size_t)(h * 64) * Kdim, d + h * 4096);
  };
  auto STAGE_B = [&](int buf, int t) {       // 3 loads: rows 0..191
    unsigned short* d = &L[buf][16384 + tid * 8];
    const unsigned short* s = Bsrc + t * 64;
#pragma unroll
    for (int h = 0; h < 3; ++h)
      gload_lds16(s + (size_t)(h * 64) * Kdim, d + h * 4096);
  };

  const int pc0 = quad ^ (lr & 7);
  const int pc1 = (4 + quad) ^ (lr & 7);
  const int aoff = (wm * 128 + lr) * 64;
  const int boff = 16384 + (wn * 48 + lr) * 64;

  // prologue: A(0), B(0) -> buf0; B(1) -> buf1; drain all but B(1)'s 3
  STAGE_A(0, 0);
  STAGE_B(0, 0);
  STAGE_B(1, 1);
  asm volatile("s_waitcnt vmcnt(3)" ::: "memory");
  G_BAR();

  short8 Af[4][2], Bf[3][2];

  for (int t = 0; t < NT; ++t) {
    const int cur = t & 1, nxt = cur ^ 1;
    // ---- phase 0: read A[0..3]+B[0..2]; stage A(t+1); mfma m0-3 x n0-2
#pragma unroll
    for (int m = 0; m < 4; ++m) {
      Af[m][0] = *(const short8*)&L[cur][aoff + m * 1024 + pc0 * 8];
      Af[m][1] = *(const short8*)&L[cur][aoff + m * 1024 + pc1 * 8];
    }
#pragma unroll
    for (int n = 0; n < 3; ++n) {
      Bf[n][0] = *(const short8*)&L[cur][boff + n * 1024 + pc0 * 8];
      Bf[n][1] = *(const short8*)&L[cur][boff + n * 1024 + pc1 * 8];
    }
    if (t + 1 < NT) STAGE_A(nxt, t + 1);
    G_BAR();
    __builtin_amdgcn_s_setprio(1);
#pragma unroll
    for (int m = 0; m < 4; ++m)
#pragma unroll
      for (int n = 0; n < 3; ++n) {
        G_MFMA(acc[m][n], Af[m][0], Bf[n][0]);
        G_MFMA(acc[m][n], Af[m][1], Bf[n][1]);
      }
    __builtin_amdgcn_s_setprio(0);
    G_BAR();
    // ---- phase 1: read A[4..7]; stage B(t+2) -> cur; mfma m4-7 x n0-2
#pragma unroll
    for (int m = 0; m < 4; ++m) {
      Af[m][0] = *(const short8*)&L[cur][aoff + (m + 4) * 1024 + pc0 * 8];
      Af[m][1] = *(const short8*)&L[cur][aoff + (m + 4) * 1024 + pc1 * 8];
    }
    if (t + 2 < NT) STAGE_B(cur, t + 2);
    G_BAR();
    __builtin_amdgcn_s_setprio(1);
#pragma unroll
    for (int m = 0; m < 4; ++m)
#pragma unroll
      for (int n = 0; n < 3; ++n) {
        G_MFMA(acc[m + 4][n], Af[m][0], Bf[n][0]);
        G_MFMA(acc[m + 4][n], Af[m][1], Bf[n][1]);
      }
    __builtin_amdgcn_s_setprio(0);
    if (t < NT - 2) { asm volatile("s_waitcnt vmcnt(3)" ::: "memory"); }
    else            { asm volatile("s_waitcnt vmcnt(0)" ::: "memory"); }
    G_BAR();
  }

  // ---- epilogue: route per n-frag (mat uniform within each 16-wide frag)
#pragma unroll
  for (int ni = 0; ni < 3; ++ni) {
    const int n = n0 + wn * 48 + ni * 16 + lr;
    const int mat = n >> 11;
    const int nl = n & 2047;
    const int h = nl >> 7, d = nl & 127;
    const float bv = (mat == 0 ? bq_ : mat == 1 ? bk_ : bv_)[nl];
    if (mat == 2) {
      // V^T: out[(b,h,d,t)]; 4 consecutive t per acc quad -> 8B stores
#pragma unroll
      for (int mi = 0; mi < 8; ++mi) {
        const int m = m0 + wm * 128 + mi * 16 + quad * 4;
        const int b = m >> 11, tt = m & 2047;
        unsigned short o4[4];
#pragma unroll
        for (int r = 0; r < 4; ++r) o4[r] = f2bf(acc[mi][ni][r] + bv);
        *(unsigned long long*)&Vo[(((size_t)(b * NH + h)) * HD + d) * Tn + tt] =
            *(const unsigned long long*)o4;
      }
    } else {
      unsigned short* Out = (mat == 0) ? Qo : Ko;
#pragma unroll
      for (int mi = 0; mi < 8; ++mi) {
#pragma unroll
        for (int r = 0; r < 4; ++r) {
          const int m = m0 + wm * 128 + mi * 16 + quad * 4 + r;
          const int b = m >> 11, tt = m & 2047;
          Out[(((size_t)(b * NH + h)) * Tn + tt) * HD + d] = f2bf(acc[mi][ni][r] + bv);
        }
      }
    }
  }
}

// ---------------- output projection GEMM (fp32 out), 256x128 ----------------
// grid (16, 8, 2) = 256 blocks = 1 exact round. 8 waves 2M x 4N, BK=64.
__global__ __launch_bounds__(512, 2) void gemm_proj_256x128_kernel(
    const unsigned short* __restrict__ Aall,  // (B, 2048, 2048)
    const unsigned short* __restrict__ Wp_,   // (N=C, K) bf16
    const float* __restrict__ bias,
    float* __restrict__ Y) {                  // (B, 2048, 2048) fp32
  constexpr int NT = Kdim / 64;
  __shared__ unsigned short L[2][24576];  // [A 16384 | B 8192]

  const int tid = threadIdx.x;
  const int wave = tid >> 6, lane = tid & 63;
  const int wm = wave >> 2, wn = wave & 3;
  const int quad = lane >> 4, lr = lane & 15;

  const int flat = (int)blockIdx.x + 16 * (int)blockIdx.y;
  const int swz = (flat & 7) * 16 + (flat >> 3);
  const int bx = swz % 16, by = swz / 16;
  const int m0 = by * 256, n0 = bx * 128;
  const int bz = blockIdx.z;
  const unsigned short* A = Aall + (size_t)bz * Cn * Tn;

  f32x4 acc[8][2];
  const f32x4 zero4 = {0.f, 0.f, 0.f, 0.f};
#pragma unroll
  for (int i = 0; i < 8; ++i)
#pragma unroll
    for (int j = 0; j < 2; ++j) acc[i][j] = zero4;

  const int srow = tid >> 3;
  const int schunk = (tid & 7) ^ (srow & 7);
  const unsigned short* Asrc = A + (size_t)(m0 + srow) * Kdim + schunk * 8;
  const unsigned short* Bsrc = Wp_ + (size_t)(n0 + srow) * Kdim + schunk * 8;

  auto STAGE_A = [&](int buf, int h, int t) {
    unsigned short* d = &L[buf][h * 8192 + tid * 8];
    const unsigned short* s = Asrc + (size_t)(h * 128) * Kdim + t * 64;
    gload_lds16(s, d);
    gload_lds16(s + (size_t)64 * Kdim, d + 4096);
  };
  auto STAGE_B = [&](int buf, int t) {
    unsigned short* d = &L[buf][16384 + tid * 8];
    const unsigned short* s = Bsrc + t * 64;
    gload_lds16(s, d);
    gload_lds16(s + (size_t)64 * Kdim, d + 4096);
  };

  const int pc0 = quad ^ (lr & 7);
  const int pc1 = (4 + quad) ^ (lr & 7);
  const int aoff = (wm * 128 + lr) * 64;
  const int boff = 16384 + (wn * 32 + lr) * 64;

  STAGE_A(0, 0, 0); STAGE_A(0, 1, 0);
  STAGE_B(0, 0);
  STAGE_B(1, 1);
  asm volatile("s_waitcnt vmcnt(2)" ::: "memory");
  G_BAR();

  short8 Af[4][2], Bf[2][2];

  for (int t = 0; t < NT; ++t) {
    const int cur = t & 1, nxt = cur ^ 1;
#pragma unroll
    for (int m = 0; m < 4; ++m) {
      Af[m][0] = *(const short8*)&L[cur][aoff + m * 1024 + pc0 * 8];
      Af[m][1] = *(const short8*)&L[cur][aoff + m * 1024 + pc1 * 8];
    }
#pragma unroll
    for (int n = 0; n < 2; ++n) {
      Bf[n][0] = *(const short8*)&L[cur][boff + n * 1024 + pc0 * 8];
      Bf[n][1] = *(const short8*)&L[cur][boff + n * 1024 + pc1 * 8];
    }
    if (t + 1 < NT) STAGE_A(nxt, 0, t + 1);
    G_BAR();
    __builtin_amdgcn_s_setprio(1);
#pragma unroll
    for (int m = 0; m < 4; ++m)
#pragma unroll
      for (int n = 0; n < 2; ++n) {
        G_MFMA(acc[m][n], Af[m][0], Bf[n][0]);
        G_MFMA(acc[m][n], Af[m][1], Bf[n][1]);
      }
    __builtin_amdgcn_s_setprio(0);
    G_BAR();
#pragma unroll
    for (int m = 0; m < 4; ++m) {
      Af[m][0] = *(const short8*)&L[cur][aoff + (m + 4) * 1024 + pc0 * 8];
      Af[m][1] = *(const short8*)&L[cur][aoff + (m + 4) * 1024 + pc1 * 8];
    }
    if (t + 1 < NT) STAGE_A(nxt, 1, t + 1);
    if (t + 2 < NT) STAGE_B(cur, t + 2);
    G_BAR();
    __builtin_amdgcn_s_setprio(1);
#pragma unroll
    for (int m = 0; m < 4; ++m)
#pragma unroll
      for (int n = 0; n < 2; ++n) {
        G_MFMA(acc[m + 4][n], Af[m][0], Bf[n][0]);
        G_MFMA(acc[m + 4][n], Af[m][1], Bf[n][1]);
      }
    __builtin_amdgcn_s_setprio(0);
    if (t < NT - 2) { asm volatile("s_waitcnt vmcnt(2)" ::: "memory"); }
    else            { asm volatile("s_waitcnt vmcnt(0)" ::: "memory"); }
    G_BAR();
  }

#pragma unroll
  for (int ni = 0; ni < 2; ++ni) {
    const int n = n0 + wn * 32 + ni * 16 + lr;
    const float bv = bias[n];
#pragma unroll
    for (int mi = 0; mi < 8; ++mi) {
#pragma unroll
      for (int r = 0; r < 4; ++r) {
        const int m = m0 + wm * 128 + mi * 16 + quad * 4 + r;
        Y[((size_t)bz * Tn + m) * Cn + n] = acc[mi][ni][r] + bv;
      }
    }
  }
}

// ---------------- flash attention (fixed-max softmax, paired q-tiles) ---
// Q,K: (BH, T, HD) bf16; V: (BH, HD, T) bf16 (written transposed by QKV).
// Output: O^T (B, H*HD, T) bf16 directly (epilogue transposes via Ps LDS).
// T14 async-STAGE split: chunk c+1 K/V loaded to regs right after the
// barrier publishing chunk c; consumed (ds_write) at next iteration top.
__global__ __launch_bounds__(256, 1) void attn_kernel(
    const unsigned short* __restrict__ Q,
    const unsigned short* __restrict__ K,
    const unsigned short* __restrict__ V,
    unsigned short* __restrict__ Ot) {
  constexpr int KST = 136;
  constexpr int VST = 136;   // 144 x 136 (rows 128..143 = ones)
  constexpr int PST = 136;   // 128 x 136 (4 waves x 32 rows)
  __shared__ unsigned short Ks[128 * KST];
  __shared__ unsigned short Vs[144 * VST];
  __shared__ unsigned short Ps[128 * PST];

  const int tid = threadIdx.x;
  const int wave = tid >> 6, lane = tid & 63;
  const int quad = lane >> 4, lr = lane & 15;
  const int bh = blockIdx.y;
  const float SL = 0.08838834764831845f * 1.4426950408889634f;  // scale*log2(e)

  const unsigned short* Kp = K + (size_t)bh * Tn * HD;
  const unsigned short* Vp = V + (size_t)bh * HD * Tn;
  unsigned short* Pw = &Ps[wave * 32 * PST];

  for (int i = tid; i < 16 * VST; i += 256) Vs[128 * VST + i] = 0x3F80;

  const int r = tid >> 1;
  const int cc = (tid & 1) * 64;
  unsigned short* kl = &Ks[r * KST + cc];
  unsigned short* vl = &Vs[r * VST + cc];
  u32x4 kreg[8], vreg[8];

  const f32x4 zero4 = {0.f, 0.f, 0.f, 0.f};
#pragma unroll 1
  for (int half = 0; half < 2; ++half) {
    const int jt = half ? (15 - (int)blockIdx.x) : (int)blockIdx.x;
    const int q0 = jt * 128;

    const unsigned short* Qp = Q + ((size_t)bh * Tn + q0 + wave * 32) * HD;
    short8 qf[2][4];
#pragma unroll
    for (int mi = 0; mi < 2; ++mi)
#pragma unroll
      for (int ks = 0; ks < 4; ++ks)
        qf[mi][ks] = *(const short8*)&Qp[(mi * 16 + lr) * HD + ks * 32 + quad * 8];

    f32x4 oacc[2][9];
#pragma unroll
    for (int mi = 0; mi < 2; ++mi)
#pragma unroll
      for (int nd = 0; nd < 9; ++nd) oacc[mi][nd] = zero4;

    const int nch = q0 / 128 + 1;

    {
      const unsigned short* kg = &Kp[(size_t)r * HD + cc];
      const unsigned short* vg = &Vp[(size_t)r * Tn + cc];
#pragma unroll
      for (int p = 0; p < 8; ++p) {
        kreg[p] = *(const u32x4*)(kg + p * 8);
        vreg[p] = *(const u32x4*)(vg + p * 8);
      }
    }

    for (int c = 0; c < nch; ++c) {
      const int k0 = c * 128;
#pragma unroll
      for (int p = 0; p < 8; ++p) {
        *(u32x4*)(kl + p * 8) = kreg[p];
        *(u32x4*)(vl + p * 8) = vreg[p];
      }
      __syncthreads();
      if (c + 1 < nch) {
        const int k1 = k0 + 128;
        const unsigned short* kg = &Kp[(size_t)(k1 + r) * HD + cc];
        const unsigned short* vg = &Vp[(size_t)r * Tn + k1 + cc];
#pragma unroll
        for (int p = 0; p < 8; ++p) {
          kreg[p] = *(const u32x4*)(kg + p * 8);
          vreg[p] = *(const u32x4*)(vg + p * 8);
        }
      }

      f32x4 sa[2][8];
#pragma unroll
      for (int mi = 0; mi < 2; ++mi)
#pragma unroll
        for (int nt = 0; nt < 8; ++nt) sa[mi][nt] = zero4;
#pragma unroll
      for (int nt = 0; nt < 8; ++nt) {
        short8 kf[4];
#pragma unroll
        for (int ks = 0; ks < 4; ++ks)
          kf[ks] = *(const short8*)&Ks[(nt * 16 + lr) * KST + ks * 32 + quad * 8];
#pragma unroll
        for (int mi = 0; mi < 2; ++mi)
#pragma unroll
          for (int ks = 0; ks < 4; ++ks)
            sa[mi][nt] = __builtin_amdgcn_mfma_f32_16x16x32_bf16(qf[mi][ks], kf[ks], sa[mi][nt], 0, 0, 0);
      }

      if (k0 == q0) {
#pragma unroll
        for (int mi = 0; mi < 2; ++mi)
#pragma unroll
          for (int nt = 0; nt < 8; ++nt)
#pragma unroll
            for (int r2 = 0; r2 < 4; ++r2) {
              const int qg = q0 + wave * 32 + mi * 16 + quad * 4 + r2;
              const int kg = k0 + nt * 16 + lr;
              if (kg > qg) sa[mi][nt][r2] = -3.0e38f;
            }
      }

#pragma unroll
      for (int mi = 0; mi < 2; ++mi)
#pragma unroll
        for (int nt = 0; nt < 8; ++nt)
#pragma unroll
          for (int r2 = 0; r2 < 4; ++r2) {
            const float p = __builtin_amdgcn_exp2f(sa[mi][nt][r2] * SL);
            Pw[(mi * 16 + quad * 4 + r2) * PST + nt * 16 + lr] = f2bf(p);
          }

#pragma unroll
      for (int kt = 0; kt < 4; ++kt) {
        short8 pf[2];
#pragma unroll
        for (int mi = 0; mi < 2; ++mi)
          pf[mi] = *(const short8*)&Pw[(mi * 16 + lr) * PST + kt * 32 + quad * 8];
#pragma unroll
        for (int nd = 0; nd < 9; ++nd) {
          short8 vf = *(const short8*)&Vs[(nd * 16 + lr) * VST + kt * 32 + quad * 8];
#pragma unroll
          for (int mi = 0; mi < 2; ++mi)
            oacc[mi][nd] = __builtin_amdgcn_mfma_f32_16x16x32_bf16(pf[mi], vf, oacc[mi][nd], 0, 0, 0);
        }
      }
      __syncthreads();
    }

    // epilogue: normalize, stage into Ps (t-major), write O^T coalesced
#pragma unroll
    for (int mi = 0; mi < 2; ++mi)
#pragma unroll
      for (int r2 = 0; r2 < 4; ++r2) {
        const float rl = 1.0f / oacc[mi][8][r2];
        const int tl = wave * 32 + mi * 16 + quad * 4 + r2;
#pragma unroll
        for (int nd = 0; nd < 8; ++nd)
          Ps[tl * PST + nd * 16 + lr] = f2bf(oacc[mi][nd][r2] * rl);
      }
    __syncthreads();
    {
      unsigned short* Od = Ot + (size_t)bh * HD * Tn + q0;  // row = d, stride Tn
#pragma unroll
      for (int p = 0; p < 8; ++p) {
        const int d = p * 16 + (tid >> 4);
        const int t8 = (tid & 15) * 8;
        alignas(16) unsigned short v[8];
#pragma unroll
        for (int j = 0; j < 8; ++j) v[j] = Ps[(t8 + j) * PST + d];
        *(u32x4*)&Od[(size_t)d * Tn + t8] = *(const u32x4*)v;
      }
    }
    __syncthreads();
  }
}

extern "C" void kernel_launch(void* const* d_in, const int* in_sizes, int n_in,
                              void* d_out, int out_size, void* d_ws, size_t ws_size,
                              hipStream_t stream) {
  const float* x  = (const float*)d_in[0];
  const float* Wq = (const float*)d_in[1];
  const float* bq = (const float*)d_in[2];
  const float* Wk = (const float*)d_in[3];
  const float* bk = (const float*)d_in[4];
  const float* Wv = (const float*)d_in[5];
  const float* bv = (const float*)d_in[6];
  const float* Wp = (const float*)d_in[7];
  const float* bp = (const float*)d_in[8];
  float* out = (float*)d_out;

  char* ws = (char*)d_ws;
  const size_t MB = 1ull << 20;
  unsigned short* Xbf = (unsigned short*)(ws);             // 16MB
  unsigned short* Wqb = (unsigned short*)(ws + 16 * MB);   // 8MB each; Wq/Wk/Wv
  unsigned short* Wkb = (unsigned short*)(ws + 24 * MB);   //  CONTIGUOUS = W3
  unsigned short* Wvb = (unsigned short*)(ws + 32 * MB);
  unsigned short* Wpb = (unsigned short*)(ws + 40 * MB);
  unsigned short* Qb  = (unsigned short*)(ws + 48 * MB);   // 16MB
  unsigned short* Kb  = (unsigned short*)(ws + 64 * MB);   // 16MB
  unsigned short* Vtb = (unsigned short*)(ws + 80 * MB);   // 16MB (B,H,D,T)
  unsigned short* Otb = (unsigned short*)(ws + 96 * MB);   // 16MB (B,H*D,T)

  cast_bf16_kernel<<<dim3(1024), dim3(256), 0, stream>>>(x, Xbf, Bn * Tn * Cn);
  cast4_kernel<<<dim3(512, 4), dim3(256), 0, stream>>>(
      Wq, Wk, Wv, Wp, Wqb, Wkb, Wvb, Wpb, Cn * Cn);

  gemm_qkv_256x192_kernel<<<dim3(32, 16), dim3(512), 0, stream>>>(
      Xbf, Wqb /* = W3 base */, bq, bk, bv, Qb, Kb, Vtb);

  attn_kernel<<<dim3(8, Bn * NH), dim3(256), 0, stream>>>(Qb, Kb, Vtb, Otb);

  gemm_proj_256x128_kernel<<<dim3(16, 8, 2), dim3(512), 0, stream>>>(
      Otb, Wpb, bp, out);
}

// Round 7
// 373.190 us; speedup vs baseline: 1.1823x; 1.0610x over previous
//
#include <hip/hip_runtime.h>
#include <stdint.h>

#define DEVI __device__ __forceinline__

typedef __attribute__((ext_vector_type(8))) short short8;
typedef __attribute__((ext_vector_type(4))) float f32x4;
typedef __attribute__((ext_vector_type(4))) unsigned int u32x4;

static constexpr int Bn = 2;
static constexpr int Tn = 2048;
static constexpr int Cn = 2048;
static constexpr int NH = 16;
static constexpr int HD = 128;
static constexpr int Kdim = 2048;

DEVI unsigned short f2bf(float f) {
  union { float f; unsigned u; } v; v.f = f;
  return (unsigned short)((v.u + 0x7FFFu + ((v.u >> 16) & 1u)) >> 16);
}

DEVI void gload_lds16(const void* g, void* l) {
  __builtin_amdgcn_global_load_lds(
      (const __attribute__((address_space(1))) void*)g,
      (__attribute__((address_space(3))) void*)l, 16, 0, 0);
}

// ---------------- cast fp32 -> bf16 (RNE) ----------------
__global__ __launch_bounds__(256) void cast_bf16_kernel(
    const float* __restrict__ src, unsigned short* __restrict__ dst, int n) {
  int idx = (blockIdx.x * blockDim.x + threadIdx.x) * 4;
  const int stride = gridDim.x * blockDim.x * 4;
  for (; idx < n; idx += stride) {
    f32x4 f = *(const f32x4*)(src + idx);
    unsigned short o[4];
    o[0] = f2bf(f[0]); o[1] = f2bf(f[1]); o[2] = f2bf(f[2]); o[3] = f2bf(f[3]);
    *(unsigned long long*)(dst + idx) = *(const unsigned long long*)o;
  }
}

__global__ __launch_bounds__(256) void cast4_kernel(
    const float* __restrict__ s0, const float* __restrict__ s1,
    const float* __restrict__ s2, const float* __restrict__ s3,
    unsigned short* __restrict__ d0, unsigned short* __restrict__ d1,
    unsigned short* __restrict__ d2, unsigned short* __restrict__ d3, int n) {
  const int w = blockIdx.y;
  const float* src = (w == 0) ? s0 : (w == 1) ? s1 : (w == 2) ? s2 : s3;
  unsigned short* dst = (w == 0) ? d0 : (w == 1) ? d1 : (w == 2) ? d2 : d3;
  int idx = (blockIdx.x * blockDim.x + threadIdx.x) * 4;
  const int stride = gridDim.x * blockDim.x * 4;
  for (; idx < n; idx += stride) {
    f32x4 f = *(const f32x4*)(src + idx);
    unsigned short o[4];
    o[0] = f2bf(f[0]); o[1] = f2bf(f[1]); o[2] = f2bf(f[2]); o[3] = f2bf(f[3]);
    *(unsigned long long*)(dst + idx) = *(const unsigned long long*)o;
  }
}

#define G_BAR() __builtin_amdgcn_s_barrier()
#define G_MFMA(d, a, b) d = __builtin_amdgcn_mfma_f32_16x16x32_bf16(a, b, d, 0, 0, 0)

// ---------------- fused QKV projection GEMM: 256x192 over W3 ----------------
// (unchanged from r5: 512 blocks = exactly 2 rounds, 860 TF)
__global__ __launch_bounds__(512, 2) void gemm_qkv_256x192_kernel(
    const unsigned short* __restrict__ X,
    const unsigned short* __restrict__ W3,
    const float* __restrict__ bq_, const float* __restrict__ bk_, const float* __restrict__ bv_,
    unsigned short* __restrict__ Qo, unsigned short* __restrict__ Ko,
    unsigned short* __restrict__ Vo) {
  constexpr int NT = Kdim / 64;  // 32 K-tiles
  __shared__ unsigned short L[2][28672];  // [A 16384 | B 12288] shorts

  const int tid = threadIdx.x;
  const int wave = tid >> 6, lane = tid & 63;
  const int wm = wave >> 2, wn = wave & 3;   // 2M x 4N
  const int quad = lane >> 4, lr = lane & 15;

  const int flat = (int)blockIdx.x + 32 * (int)blockIdx.y;
  const int swz = (flat & 7) * 64 + (flat >> 3);
  const int bx = swz & 31, by = swz >> 5;
  const int n0 = bx * 192;                   // global n in [0, 6144)
  const int m0 = by * 256;

  f32x4 acc[8][3];
  const f32x4 zero4 = {0.f, 0.f, 0.f, 0.f};
#pragma unroll
  for (int i = 0; i < 8; ++i)
#pragma unroll
    for (int j = 0; j < 3; ++j) acc[i][j] = zero4;

  const int srow = tid >> 3;                 // 0..63
  const int schunk = (tid & 7) ^ (srow & 7);
  const unsigned short* Asrc = X + (size_t)(m0 + srow) * Kdim + schunk * 8;
  const unsigned short* Bsrc = W3 + (size_t)(n0 + srow) * Kdim + schunk * 8;

  auto STAGE_A = [&](int buf, int t) {       // 4 loads: rows 0..255
    unsigned short* d = &L[buf][tid * 8];
    const unsigned short* s = Asrc + t * 64;
#pragma unroll
    for (int h = 0; h < 4; ++h)
      gload_lds16(s + (size_t)(h * 64) * Kdim, d + h * 4096);
  };
  auto STAGE_B = [&](int buf, int t) {       // 3 loads: rows 0..191
    unsigned short* d = &L[buf][16384 + tid * 8];
    const unsigned short* s = Bsrc + t * 64;
#pragma unroll
    for (int h = 0; h < 3; ++h)
      gload_lds16(s + (size_t)(h * 64) * Kdim, d + h * 4096);
  };

  const int pc0 = quad ^ (lr & 7);
  const int pc1 = (4 + quad) ^ (lr & 7);
  const int aoff = (wm * 128 + lr) * 64;
  const int boff = 16384 + (wn * 48 + lr) * 64;

  STAGE_A(0, 0);
  STAGE_B(0, 0);
  STAGE_B(1, 1);
  asm volatile("s_waitcnt vmcnt(3)" ::: "memory");
  G_BAR();

  short8 Af[4][2], Bf[3][2];

  for (int t = 0; t < NT; ++t) {
    const int cur = t & 1, nxt = cur ^ 1;
#pragma unroll
    for (int m = 0; m < 4; ++m) {
      Af[m][0] = *(const short8*)&L[cur][aoff + m * 1024 + pc0 * 8];
      Af[m][1] = *(const short8*)&L[cur][aoff + m * 1024 + pc1 * 8];
    }
#pragma unroll
    for (int n = 0; n < 3; ++n) {
      Bf[n][0] = *(const short8*)&L[cur][boff + n * 1024 + pc0 * 8];
      Bf[n][1] = *(const short8*)&L[cur][boff + n * 1024 + pc1 * 8];
    }
    if (t + 1 < NT) STAGE_A(nxt, t + 1);
    G_BAR();
    __builtin_amdgcn_s_setprio(1);
#pragma unroll
    for (int m = 0; m < 4; ++m)
#pragma unroll
      for (int n = 0; n < 3; ++n) {
        G_MFMA(acc[m][n], Af[m][0], Bf[n][0]);
        G_MFMA(acc[m][n], Af[m][1], Bf[n][1]);
      }
    __builtin_amdgcn_s_setprio(0);
    G_BAR();
#pragma unroll
    for (int m = 0; m < 4; ++m) {
      Af[m][0] = *(const short8*)&L[cur][aoff + (m + 4) * 1024 + pc0 * 8];
      Af[m][1] = *(const short8*)&L[cur][aoff + (m + 4) * 1024 + pc1 * 8];
    }
    if (t + 2 < NT) STAGE_B(cur, t + 2);
    G_BAR();
    __builtin_amdgcn_s_setprio(1);
#pragma unroll
    for (int m = 0; m < 4; ++m)
#pragma unroll
      for (int n = 0; n < 3; ++n) {
        G_MFMA(acc[m + 4][n], Af[m][0], Bf[n][0]);
        G_MFMA(acc[m + 4][n], Af[m][1], Bf[n][1]);
      }
    __builtin_amdgcn_s_setprio(0);
    if (t < NT - 2) { asm volatile("s_waitcnt vmcnt(3)" ::: "memory"); }
    else            { asm volatile("s_waitcnt vmcnt(0)" ::: "memory"); }
    G_BAR();
  }

#pragma unroll
  for (int ni = 0; ni < 3; ++ni) {
    const int n = n0 + wn * 48 + ni * 16 + lr;
    const int mat = n >> 11;
    const int nl = n & 2047;
    const int h = nl >> 7, d = nl & 127;
    const float bv = (mat == 0 ? bq_ : mat == 1 ? bk_ : bv_)[nl];
    if (mat == 2) {
#pragma unroll
      for (int mi = 0; mi < 8; ++mi) {
        const int m = m0 + wm * 128 + mi * 16 + quad * 4;
        const int b = m >> 11, tt = m & 2047;
        unsigned short o4[4];
#pragma unroll
        for (int r = 0; r < 4; ++r) o4[r] = f2bf(acc[mi][ni][r] + bv);
        *(unsigned long long*)&Vo[(((size_t)(b * NH + h)) * HD + d) * Tn + tt] =
            *(const unsigned long long*)o4;
      }
    } else {
      unsigned short* Out = (mat == 0) ? Qo : Ko;
#pragma unroll
      for (int mi = 0; mi < 8; ++mi) {
#pragma unroll
        for (int r = 0; r < 4; ++r) {
          const int m = m0 + wm * 128 + mi * 16 + quad * 4 + r;
          const int b = m >> 11, tt = m & 2047;
          Out[(((size_t)(b * NH + h)) * Tn + tt) * HD + d] = f2bf(acc[mi][ni][r] + bv);
        }
      }
    }
  }
}

// ---------------- output projection GEMM (fp32 out), 256x128 ----------------
__global__ __launch_bounds__(512, 2) void gemm_proj_256x128_kernel(
    const unsigned short* __restrict__ Aall,
    const unsigned short* __restrict__ Wp_,
    const float* __restrict__ bias,
    float* __restrict__ Y) {
  constexpr int NT = Kdim / 64;
  __shared__ unsigned short L[2][24576];

  const int tid = threadIdx.x;
  const int wave = tid >> 6, lane = tid & 63;
  const int wm = wave >> 2, wn = wave & 3;
  const int quad = lane >> 4, lr = lane & 15;

  const int flat = (int)blockIdx.x + 16 * (int)blockIdx.y;
  const int swz = (flat & 7) * 16 + (flat >> 3);
  const int bx = swz % 16, by = swz / 16;
  const int m0 = by * 256, n0 = bx * 128;
  const int bz = blockIdx.z;
  const unsigned short* A = Aall + (size_t)bz * Cn * Tn;

  f32x4 acc[8][2];
  const f32x4 zero4 = {0.f, 0.f, 0.f, 0.f};
#pragma unroll
  for (int i = 0; i < 8; ++i)
#pragma unroll
    for (int j = 0; j < 2; ++j) acc[i][j] = zero4;

  const int srow = tid >> 3;
  const int schunk = (tid & 7) ^ (srow & 7);
  const unsigned short* Asrc = A + (size_t)(m0 + srow) * Kdim + schunk * 8;
  const unsigned short* Bsrc = Wp_ + (size_t)(n0 + srow) * Kdim + schunk * 8;

  auto STAGE_A = [&](int buf, int h, int t) {
    unsigned short* d = &L[buf][h * 8192 + tid * 8];
    const unsigned short* s = Asrc + (size_t)(h * 128) * Kdim + t * 64;
    gload_lds16(s, d);
    gload_lds16(s + (size_t)64 * Kdim, d + 4096);
  };
  auto STAGE_B = [&](int buf, int t) {
    unsigned short* d = &L[buf][16384 + tid * 8];
    const unsigned short* s = Bsrc + t * 64;
    gload_lds16(s, d);
    gload_lds16(s + (size_t)64 * Kdim, d + 4096);
  };

  const int pc0 = quad ^ (lr & 7);
  const int pc1 = (4 + quad) ^ (lr & 7);
  const int aoff = (wm * 128 + lr) * 64;
  const int boff = 16384 + (wn * 32 + lr) * 64;

  STAGE_A(0, 0, 0); STAGE_A(0, 1, 0);
  STAGE_B(0, 0);
  STAGE_B(1, 1);
  asm volatile("s_waitcnt vmcnt(2)" ::: "memory");
  G_BAR();

  short8 Af[4][2], Bf[2][2];

  for (int t = 0; t < NT; ++t) {
    const int cur = t & 1, nxt = cur ^ 1;
#pragma unroll
    for (int m = 0; m < 4; ++m) {
      Af[m][0] = *(const short8*)&L[cur][aoff + m * 1024 + pc0 * 8];
      Af[m][1] = *(const short8*)&L[cur][aoff + m * 1024 + pc1 * 8];
    }
#pragma unroll
    for (int n = 0; n < 2; ++n) {
      Bf[n][0] = *(const short8*)&L[cur][boff + n * 1024 + pc0 * 8];
      Bf[n][1] = *(const short8*)&L[cur][boff + n * 1024 + pc1 * 8];
    }
    if (t + 1 < NT) STAGE_A(nxt, 0, t + 1);
    G_BAR();
    __builtin_amdgcn_s_setprio(1);
#pragma unroll
    for (int m = 0; m < 4; ++m)
#pragma unroll
      for (int n = 0; n < 2; ++n) {
        G_MFMA(acc[m][n], Af[m][0], Bf[n][0]);
        G_MFMA(acc[m][n], Af[m][1], Bf[n][1]);
      }
    __builtin_amdgcn_s_setprio(0);
    G_BAR();
#pragma unroll
    for (int m = 0; m < 4; ++m) {
      Af[m][0] = *(const short8*)&L[cur][aoff + (m + 4) * 1024 + pc0 * 8];
      Af[m][1] = *(const short8*)&L[cur][aoff + (m + 4) * 1024 + pc1 * 8];
    }
    if (t + 1 < NT) STAGE_A(nxt, 1, t + 1);
    if (t + 2 < NT) STAGE_B(cur, t + 2);
    G_BAR();
    __builtin_amdgcn_s_setprio(1);
#pragma unroll
    for (int m = 0; m < 4; ++m)
#pragma unroll
      for (int n = 0; n < 2; ++n) {
        G_MFMA(acc[m + 4][n], Af[m][0], Bf[n][0]);
        G_MFMA(acc[m + 4][n], Af[m][1], Bf[n][1]);
      }
    __builtin_amdgcn_s_setprio(0);
    if (t < NT - 2) { asm volatile("s_waitcnt vmcnt(2)" ::: "memory"); }
    else            { asm volatile("s_waitcnt vmcnt(0)" ::: "memory"); }
    G_BAR();
  }

#pragma unroll
  for (int ni = 0; ni < 2; ++ni) {
    const int n = n0 + wn * 32 + ni * 16 + lr;
    const float bv = bias[n];
#pragma unroll
    for (int mi = 0; mi < 8; ++mi) {
#pragma unroll
      for (int r = 0; r < 4; ++r) {
        const int m = m0 + wm * 128 + mi * 16 + quad * 4 + r;
        Y[((size_t)bz * Tn + m) * Cn + n] = acc[mi][ni][r] + bv;
      }
    }
  }
}

// ---------------- flash attention: 8-wave kv-split ----------------
// Waves (wb = wave&3: q-band of 32 rows; wh = wave>>2: kv half).
// Wave (wb,wh) computes QK^T for S cols [wh*64, wh*64+64), writes those P
// cols, and does PV over the SAME cols -> P write/read stays intra-wave
// (no extra barrier in chunk loop). oacc is a kv-partial; combined once
// per q-tile via f32x4 LDS buffer overlaid on dead Ks/Vs. LDS unchanged
// (108.8 KB, 1 block/CU) but 8 waves = 2/SIMD (was 1/SIMD, zero TLP).
// r6 fix: cbuf overlays Vs rows 128..143 (the "ones" rows) -> re-init
// them at the TOP of each half iteration, not once per kernel.
__global__ __launch_bounds__(512, 2) void attn_kernel(
    const unsigned short* __restrict__ Q,
    const unsigned short* __restrict__ K,
    const unsigned short* __restrict__ V,
    unsigned short* __restrict__ Ot) {
  constexpr int KST = 136;
  constexpr int VST = 136;   // 144 x 136 (rows 128..143 = ones)
  constexpr int PST = 136;   // 128 x 136 (4 bands x 32 rows)
  __shared__ unsigned short SMEM[54400];   // 108.8 KB
  unsigned short* Ks = SMEM;               // 128*136 = 17408
  unsigned short* Vs = SMEM + 17408;       // 144*136 = 19584
  unsigned short* Ps = SMEM + 36992;       // 128*136 = 17408

  const int tid = threadIdx.x;
  const int wave = tid >> 6, lane = tid & 63;
  const int wb = wave & 3;                 // q band
  const int wh = wave >> 2;                // kv half
  const int quad = lane >> 4, lr = lane & 15;
  const int bh = blockIdx.y;
  const float SL = 0.08838834764831845f * 1.4426950408889634f;  // scale*log2(e)

  const unsigned short* Kp = K + (size_t)bh * Tn * HD;
  const unsigned short* Vp = V + (size_t)bh * HD * Tn;
  unsigned short* Pw = &Ps[wb * 32 * PST];

  // staging geometry: 512 threads, row r = tid>>2, 32-elem quarter cc
  const int r = tid >> 2;
  const int cc = (tid & 3) * 32;
  unsigned short* kl = &Ks[r * KST + cc];
  unsigned short* vl = &Vs[r * VST + cc];
  u32x4 kreg[4], vreg[4];

  const f32x4 zero4 = {0.f, 0.f, 0.f, 0.f};
#pragma unroll 1
  for (int half = 0; half < 2; ++half) {
    const int jt = half ? (15 - (int)blockIdx.x) : (int)blockIdx.x;
    const int q0 = jt * 128;

    // re-init V "ones" rows each half (cbuf clobbers them in the combine)
    for (int i = tid; i < 16 * VST; i += 512) Vs[128 * VST + i] = 0x3F80;

    const unsigned short* Qp = Q + ((size_t)bh * Tn + q0 + wb * 32) * HD;
    short8 qf[2][4];
#pragma unroll
    for (int mi = 0; mi < 2; ++mi)
#pragma unroll
      for (int ks = 0; ks < 4; ++ks)
        qf[mi][ks] = *(const short8*)&Qp[(mi * 16 + lr) * HD + ks * 32 + quad * 8];

    f32x4 oacc[2][9];
#pragma unroll
    for (int mi = 0; mi < 2; ++mi)
#pragma unroll
      for (int nd = 0; nd < 9; ++nd) oacc[mi][nd] = zero4;

    const int nch = q0 / 128 + 1;

    // prologue: chunk 0 -> registers (T14)
    {
      const unsigned short* kg = &Kp[(size_t)r * HD + cc];
      const unsigned short* vg = &Vp[(size_t)r * Tn + cc];
#pragma unroll
      for (int p = 0; p < 4; ++p) {
        kreg[p] = *(const u32x4*)(kg + p * 8);
        vreg[p] = *(const u32x4*)(vg + p * 8);
      }
    }

    for (int c = 0; c < nch; ++c) {
      const int k0 = c * 128;
#pragma unroll
      for (int p = 0; p < 4; ++p) {
        *(u32x4*)(kl + p * 8) = kreg[p];
        *(u32x4*)(vl + p * 8) = vreg[p];
      }
      __syncthreads();
      if (c + 1 < nch) {
        const int k1 = k0 + 128;
        const unsigned short* kg = &Kp[(size_t)(k1 + r) * HD + cc];
        const unsigned short* vg = &Vp[(size_t)r * Tn + k1 + cc];
#pragma unroll
        for (int p = 0; p < 4; ++p) {
          kreg[p] = *(const u32x4*)(kg + p * 8);
          vreg[p] = *(const u32x4*)(vg + p * 8);
        }
      }

      // QK^T for this wave's nt half (4 of 8 16-col tiles)
      f32x4 sa[2][4];
#pragma unroll
      for (int mi = 0; mi < 2; ++mi)
#pragma unroll
        for (int n4 = 0; n4 < 4; ++n4) sa[mi][n4] = zero4;
#pragma unroll
      for (int n4 = 0; n4 < 4; ++n4) {
        const int nt = wh * 4 + n4;
        short8 kf[4];
#pragma unroll
        for (int ks = 0; ks < 4; ++ks)
          kf[ks] = *(const short8*)&Ks[(nt * 16 + lr) * KST + ks * 32 + quad * 8];
#pragma unroll
        for (int mi = 0; mi < 2; ++mi)
#pragma unroll
          for (int ks = 0; ks < 4; ++ks)
            sa[mi][n4] = __builtin_amdgcn_mfma_f32_16x16x32_bf16(qf[mi][ks], kf[ks], sa[mi][n4], 0, 0, 0);
      }

      if (k0 == q0) {
#pragma unroll
        for (int mi = 0; mi < 2; ++mi)
#pragma unroll
          for (int n4 = 0; n4 < 4; ++n4)
#pragma unroll
            for (int r2 = 0; r2 < 4; ++r2) {
              const int qg = q0 + wb * 32 + mi * 16 + quad * 4 + r2;
              const int kg = k0 + (wh * 4 + n4) * 16 + lr;
              if (kg > qg) sa[mi][n4][r2] = -3.0e38f;
            }
      }

#pragma unroll
      for (int mi = 0; mi < 2; ++mi)
#pragma unroll
        for (int n4 = 0; n4 < 4; ++n4)
#pragma unroll
          for (int r2 = 0; r2 < 4; ++r2) {
            const float p = __builtin_amdgcn_exp2f(sa[mi][n4][r2] * SL);
            Pw[(mi * 16 + quad * 4 + r2) * PST + (wh * 4 + n4) * 16 + lr] = f2bf(p);
          }

      // PV over this wave's kt half (2 of 4 32-col k-slices) — intra-wave P
#pragma unroll
      for (int k2 = 0; k2 < 2; ++k2) {
        const int kt = wh * 2 + k2;
        short8 pf[2];
#pragma unroll
        for (int mi = 0; mi < 2; ++mi)
          pf[mi] = *(const short8*)&Pw[(mi * 16 + lr) * PST + kt * 32 + quad * 8];
#pragma unroll
        for (int nd = 0; nd < 9; ++nd) {
          short8 vf = *(const short8*)&Vs[(nd * 16 + lr) * VST + kt * 32 + quad * 8];
#pragma unroll
          for (int mi = 0; mi < 2; ++mi)
            oacc[mi][nd] = __builtin_amdgcn_mfma_f32_16x16x32_bf16(pf[mi], vf, oacc[mi][nd], 0, 0, 0);
        }
      }
      __syncthreads();
    }

    // ---- combine kv-partials: wh==1 publish to LDS (overlays dead Ks/Vs)
    f32x4* cbuf = (f32x4*)SMEM;   // 4608 x 16B = 73728 B (clobbers ones rows)
    if (wh == 1) {
#pragma unroll
      for (int mi = 0; mi < 2; ++mi)
#pragma unroll
        for (int nd = 0; nd < 9; ++nd)
          cbuf[(wb * 64 + lane) * 18 + mi * 9 + nd] = oacc[mi][nd];
    }
    __syncthreads();
    if (wh == 0) {
#pragma unroll
      for (int mi = 0; mi < 2; ++mi)
#pragma unroll
        for (int nd = 0; nd < 9; ++nd)
          oacc[mi][nd] += cbuf[(wb * 64 + lane) * 18 + mi * 9 + nd];
      // normalize + stage into Ps (t-major)
#pragma unroll
      for (int mi = 0; mi < 2; ++mi)
#pragma unroll
        for (int r2 = 0; r2 < 4; ++r2) {
          const float rl = 1.0f / oacc[mi][8][r2];
          const int tl = wb * 32 + mi * 16 + quad * 4 + r2;
#pragma unroll
          for (int nd = 0; nd < 8; ++nd)
            Ps[tl * PST + nd * 16 + lr] = f2bf(oacc[mi][nd][r2] * rl);
        }
    }
    __syncthreads();
    if (tid < 256) {
      unsigned short* Od = Ot + (size_t)bh * HD * Tn + q0;  // row = d, stride Tn
#pragma unroll
      for (int p = 0; p < 8; ++p) {
        const int d = p * 16 + (tid >> 4);
        const int t8 = (tid & 15) * 8;
        alignas(16) unsigned short v[8];
#pragma unroll
        for (int j = 0; j < 8; ++j) v[j] = Ps[(t8 + j) * PST + d];
        *(u32x4*)&Od[(size_t)d * Tn + t8] = *(const u32x4*)v;
      }
    }
    __syncthreads();
  }
}

extern "C" void kernel_launch(void* const* d_in, const int* in_sizes, int n_in,
                              void* d_out, int out_size, void* d_ws, size_t ws_size,
                              hipStream_t stream) {
  const float* x  = (const float*)d_in[0];
  const float* Wq = (const float*)d_in[1];
  const float* bq = (const float*)d_in[2];
  const float* Wk = (const float*)d_in[3];
  const float* bk = (const float*)d_in[4];
  const float* Wv = (const float*)d_in[5];
  const float* bv = (const float*)d_in[6];
  const float* Wp = (const float*)d_in[7];
  const float* bp = (const float*)d_in[8];
  float* out = (float*)d_out;

  char* ws = (char*)d_ws;
  const size_t MB = 1ull << 20;
  unsigned short* Xbf = (unsigned short*)(ws);             // 16MB
  unsigned short* Wqb = (unsigned short*)(ws + 16 * MB);   // 8MB each; Wq/Wk/Wv
  unsigned short* Wkb = (unsigned short*)(ws + 24 * MB);   //  CONTIGUOUS = W3
  unsigned short* Wvb = (unsigned short*)(ws + 32 * MB);
  unsigned short* Wpb = (unsigned short*)(ws + 40 * MB);
  unsigned short* Qb  = (unsigned short*)(ws + 48 * MB);   // 16MB
  unsigned short* Kb  = (unsigned short*)(ws + 64 * MB);   // 16MB
  unsigned short* Vtb = (unsigned short*)(ws + 80 * MB);   // 16MB (B,H,D,T)
  unsigned short* Otb = (unsigned short*)(ws + 96 * MB);   // 16MB (B,H*D,T)

  cast_bf16_kernel<<<dim3(1024), dim3(256), 0, stream>>>(x, Xbf, Bn * Tn * Cn);
  cast4_kernel<<<dim3(512, 4), dim3(256), 0, stream>>>(
      Wq, Wk, Wv, Wp, Wqb, Wkb, Wvb, Wpb, Cn * Cn);

  gemm_qkv_256x192_kernel<<<dim3(32, 16), dim3(512), 0, stream>>>(
      Xbf, Wqb /* = W3 base */, bq, bk, bv, Qb, Kb, Vtb);

  attn_kernel<<<dim3(8, Bn * NH), dim3(512), 0, stream>>>(Qb, Kb, Vtb, Otb);

  gemm_proj_256x128_kernel<<<dim3(16, 8, 2), dim3(512), 0, stream>>>(
      Otb, Wpb, bp, out);
}

// Round 8
// 370.107 us; speedup vs baseline: 1.1922x; 1.0083x over previous
//
#include <hip/hip_runtime.h>
#include <stdint.h>

#define DEVI __device__ __forceinline__

typedef __attribute__((ext_vector_type(8))) short short8;
typedef __attribute__((ext_vector_type(4))) float f32x4;
typedef __attribute__((ext_vector_type(4))) unsigned int u32x4;

static constexpr int Bn = 2;
static constexpr int Tn = 2048;
static constexpr int Cn = 2048;
static constexpr int NH = 16;
static constexpr int HD = 128;
static constexpr int Kdim = 2048;

DEVI unsigned short f2bf(float f) {
  union { float f; unsigned u; } v; v.f = f;
  return (unsigned short)((v.u + 0x7FFFu + ((v.u >> 16) & 1u)) >> 16);
}

DEVI void gload_lds16(const void* g, void* l) {
  __builtin_amdgcn_global_load_lds(
      (const __attribute__((address_space(1))) void*)g,
      (__attribute__((address_space(3))) void*)l, 16, 0, 0);
}

// ---------------- cast fp32 -> bf16 (RNE) ----------------
__global__ __launch_bounds__(256) void cast_bf16_kernel(
    const float* __restrict__ src, unsigned short* __restrict__ dst, int n) {
  int idx = (blockIdx.x * blockDim.x + threadIdx.x) * 4;
  const int stride = gridDim.x * blockDim.x * 4;
  for (; idx < n; idx += stride) {
    f32x4 f = *(const f32x4*)(src + idx);
    unsigned short o[4];
    o[0] = f2bf(f[0]); o[1] = f2bf(f[1]); o[2] = f2bf(f[2]); o[3] = f2bf(f[3]);
    *(unsigned long long*)(dst + idx) = *(const unsigned long long*)o;
  }
}

__global__ __launch_bounds__(256) void cast4_kernel(
    const float* __restrict__ s0, const float* __restrict__ s1,
    const float* __restrict__ s2, const float* __restrict__ s3,
    unsigned short* __restrict__ d0, unsigned short* __restrict__ d1,
    unsigned short* __restrict__ d2, unsigned short* __restrict__ d3, int n) {
  const int w = blockIdx.y;
  const float* src = (w == 0) ? s0 : (w == 1) ? s1 : (w == 2) ? s2 : s3;
  unsigned short* dst = (w == 0) ? d0 : (w == 1) ? d1 : (w == 2) ? d2 : d3;
  int idx = (blockIdx.x * blockDim.x + threadIdx.x) * 4;
  const int stride = gridDim.x * blockDim.x * 4;
  for (; idx < n; idx += stride) {
    f32x4 f = *(const f32x4*)(src + idx);
    unsigned short o[4];
    o[0] = f2bf(f[0]); o[1] = f2bf(f[1]); o[2] = f2bf(f[2]); o[3] = f2bf(f[3]);
    *(unsigned long long*)(dst + idx) = *(const unsigned long long*)o;
  }
}

#define G_BAR() __builtin_amdgcn_s_barrier()
#define G_MFMA(d, a, b) d = __builtin_amdgcn_mfma_f32_16x16x32_bf16(a, b, d, 0, 0, 0)

// ---------------- fused QKV projection GEMM: 256x192 over W3, 4-phase ----
// r7: same geometry as the passing r5/r7 kernel (512 blocks = exactly 2
// rounds, LDS 112 KB, 8 waves 2Mx4N, wave-tile 128x48, BK=64, chunk-XOR
// swizzle), but K-tile split into 4 phases of 12 MFMA (T3+T4 granularity):
//   ph0: rd A[0-3].h0 + B[0-2].h0 | stage A(t+1) rows 0-127   | 12 MFMA
//   ph1: rd A[0-3].h1 + B[0-2].h1 | stage A(t+1) rows 128-255 | 12 MFMA
//   ph2: rd A[4-7].h0             | stage B(t+2) rows 0-127   | 12 MFMA
//   ph3: rd A[4-7].h1             | stage B(t+2) rows 128-191 | 12 MFMA, vmcnt(3)
// Ledger (steady state): entering tile t, B(t+1)'s 3 loads in flight;
// tile t issues A(t+1) 4 + B(t+2) 3; boundary vmcnt(3) drains the 7
// oldest = B(t+1)+A(t+1), leaving B(t+2) 3. Hazards: B(t+2)->cur issued
// ph2 (all B(t) reads in regs before ph1 MFMA's lgkmcnt); A(t+1)->nxt
// after tile t-1's final barrier. Bf holds both k-halves across phases.
__global__ __launch_bounds__(512, 2) void gemm_qkv_256x192_kernel(
    const unsigned short* __restrict__ X,
    const unsigned short* __restrict__ W3,
    const float* __restrict__ bq_, const float* __restrict__ bk_, const float* __restrict__ bv_,
    unsigned short* __restrict__ Qo, unsigned short* __restrict__ Ko,
    unsigned short* __restrict__ Vo) {
  constexpr int NT = Kdim / 64;  // 32 K-tiles
  __shared__ unsigned short L[2][28672];  // [A 16384 | B 12288] shorts

  const int tid = threadIdx.x;
  const int wave = tid >> 6, lane = tid & 63;
  const int wm = wave >> 2, wn = wave & 3;   // 2M x 4N
  const int quad = lane >> 4, lr = lane & 15;

  const int flat = (int)blockIdx.x + 32 * (int)blockIdx.y;
  const int swz = (flat & 7) * 64 + (flat >> 3);
  const int bx = swz & 31, by = swz >> 5;
  const int n0 = bx * 192;                   // global n in [0, 6144)
  const int m0 = by * 256;

  f32x4 acc[8][3];
  const f32x4 zero4 = {0.f, 0.f, 0.f, 0.f};
#pragma unroll
  for (int i = 0; i < 8; ++i)
#pragma unroll
    for (int j = 0; j < 3; ++j) acc[i][j] = zero4;

  const int srow = tid >> 3;                 // 0..63
  const int schunk = (tid & 7) ^ (srow & 7);
  const unsigned short* Asrc = X + (size_t)(m0 + srow) * Kdim + schunk * 8;
  const unsigned short* Bsrc = W3 + (size_t)(n0 + srow) * Kdim + schunk * 8;

  auto STAGE_A2 = [&](int buf, int h, int t) {  // rows h*128 .. h*128+127
    unsigned short* d = &L[buf][h * 8192 + tid * 8];
    const unsigned short* s = Asrc + (size_t)(h * 128) * Kdim + t * 64;
    gload_lds16(s, d);
    gload_lds16(s + (size_t)64 * Kdim, d + 4096);
  };
  auto STAGE_B2 = [&](int buf, int t) {         // rows 0..127
    unsigned short* d = &L[buf][16384 + tid * 8];
    const unsigned short* s = Bsrc + t * 64;
    gload_lds16(s, d);
    gload_lds16(s + (size_t)64 * Kdim, d + 4096);
  };
  auto STAGE_B1 = [&](int buf, int t) {         // rows 128..191
    unsigned short* d = &L[buf][16384 + 8192 + tid * 8];
    const unsigned short* s = Bsrc + (size_t)128 * Kdim + t * 64;
    gload_lds16(s, d);
  };

  const int pc0 = quad ^ (lr & 7);
  const int pc1 = (4 + quad) ^ (lr & 7);
  const int aoff = (wm * 128 + lr) * 64;
  const int boff = 16384 + (wn * 48 + lr) * 64;
#define RDA(mi, pc) (*(const short8*)&L[cur][aoff + (mi) * 1024 + (pc) * 8])
#define RDB(ni, pc) (*(const short8*)&L[cur][boff + (ni) * 1024 + (pc) * 8])

  // prologue: A(0), B(0) -> buf0; B(1) -> buf1; drain all but B(1)'s 3
  STAGE_A2(0, 0, 0); STAGE_A2(0, 1, 0);
  STAGE_B2(0, 0); STAGE_B1(0, 0);
  STAGE_B2(1, 1); STAGE_B1(1, 1);
  asm volatile("s_waitcnt vmcnt(3)" ::: "memory");
  G_BAR();

  short8 Af[4], Bf[3][2];

  for (int t = 0; t < NT; ++t) {
    const int cur = t & 1, nxt = cur ^ 1;
    // ---- ph0: rd A[0-3].h0 + B.h0; stage A(t+1) half0; mfma m0-3 h0
#pragma unroll
    for (int m = 0; m < 4; ++m) Af[m] = RDA(m, pc0);
#pragma unroll
    for (int n = 0; n < 3; ++n) Bf[n][0] = RDB(n, pc0);
    if (t + 1 < NT) STAGE_A2(nxt, 0, t + 1);
    G_BAR();
    __builtin_amdgcn_s_setprio(1);
#pragma unroll
    for (int m = 0; m < 4; ++m)
#pragma unroll
      for (int n = 0; n < 3; ++n) G_MFMA(acc[m][n], Af[m], Bf[n][0]);
    __builtin_amdgcn_s_setprio(0);
    G_BAR();
    // ---- ph1: rd A[0-3].h1 + B.h1; stage A(t+1) half1; mfma m0-3 h1
#pragma unroll
    for (int m = 0; m < 4; ++m) Af[m] = RDA(m, pc1);
#pragma unroll
    for (int n = 0; n < 3; ++n) Bf[n][1] = RDB(n, pc1);
    if (t + 1 < NT) STAGE_A2(nxt, 1, t + 1);
    G_BAR();
    __builtin_amdgcn_s_setprio(1);
#pragma unroll
    for (int m = 0; m < 4; ++m)
#pragma unroll
      for (int n = 0; n < 3; ++n) G_MFMA(acc[m][n], Af[m], Bf[n][1]);
    __builtin_amdgcn_s_setprio(0);
    G_BAR();
    // ---- ph2: rd A[4-7].h0; stage B(t+2) half0; mfma m4-7 h0
#pragma unroll
    for (int m = 0; m < 4; ++m) Af[m] = RDA(m + 4, pc0);
    if (t + 2 < NT) STAGE_B2(cur, t + 2);
    G_BAR();
    __builtin_amdgcn_s_setprio(1);
#pragma unroll
    for (int m = 0; m < 4; ++m)
#pragma unroll
      for (int n = 0; n < 3; ++n) G_MFMA(acc[m + 4][n], Af[m], Bf[n][0]);
    __builtin_amdgcn_s_setprio(0);
    G_BAR();
    // ---- ph3: rd A[4-7].h1; stage B(t+2) last; mfma m4-7 h1
#pragma unroll
    for (int m = 0; m < 4; ++m) Af[m] = RDA(m + 4, pc1);
    if (t + 2 < NT) STAGE_B1(cur, t + 2);
    G_BAR();
    __builtin_amdgcn_s_setprio(1);
#pragma unroll
    for (int m = 0; m < 4; ++m)
#pragma unroll
      for (int n = 0; n < 3; ++n) G_MFMA(acc[m + 4][n], Af[m], Bf[n][1]);
    __builtin_amdgcn_s_setprio(0);
    if (t < NT - 2) { asm volatile("s_waitcnt vmcnt(3)" ::: "memory"); }
    else            { asm volatile("s_waitcnt vmcnt(0)" ::: "memory"); }
    G_BAR();
  }
#undef RDA
#undef RDB

#pragma unroll
  for (int ni = 0; ni < 3; ++ni) {
    const int n = n0 + wn * 48 + ni * 16 + lr;
    const int mat = n >> 11;
    const int nl = n & 2047;
    const int h = nl >> 7, d = nl & 127;
    const float bv = (mat == 0 ? bq_ : mat == 1 ? bk_ : bv_)[nl];
    if (mat == 2) {
#pragma unroll
      for (int mi = 0; mi < 8; ++mi) {
        const int m = m0 + wm * 128 + mi * 16 + quad * 4;
        const int b = m >> 11, tt = m & 2047;
        unsigned short o4[4];
#pragma unroll
        for (int r = 0; r < 4; ++r) o4[r] = f2bf(acc[mi][ni][r] + bv);
        *(unsigned long long*)&Vo[(((size_t)(b * NH + h)) * HD + d) * Tn + tt] =
            *(const unsigned long long*)o4;
      }
    } else {
      unsigned short* Out = (mat == 0) ? Qo : Ko;
#pragma unroll
      for (int mi = 0; mi < 8; ++mi) {
#pragma unroll
        for (int r = 0; r < 4; ++r) {
          const int m = m0 + wm * 128 + mi * 16 + quad * 4 + r;
          const int b = m >> 11, tt = m & 2047;
          Out[(((size_t)(b * NH + h)) * Tn + tt) * HD + d] = f2bf(acc[mi][ni][r] + bv);
        }
      }
    }
  }
}

// ---------------- output projection GEMM (fp32 out), 256x128 ----------------
// (unchanged from r5/r7 passing version; grid 256 blocks = 1 exact round)
__global__ __launch_bounds__(512, 2) void gemm_proj_256x128_kernel(
    const unsigned short* __restrict__ Aall,
    const unsigned short* __restrict__ Wp_,
    const float* __restrict__ bias,
    float* __restrict__ Y) {
  constexpr int NT = Kdim / 64;
  __shared__ unsigned short L[2][24576];

  const int tid = threadIdx.x;
  const int wave = tid >> 6, lane = tid & 63;
  const int wm = wave >> 2, wn = wave & 3;
  const int quad = lane >> 4, lr = lane & 15;

  const int flat = (int)blockIdx.x + 16 * (int)blockIdx.y;
  const int swz = (flat & 7) * 16 + (flat >> 3);
  const int bx = swz % 16, by = swz / 16;
  const int m0 = by * 256, n0 = bx * 128;
  const int bz = blockIdx.z;
  const unsigned short* A = Aall + (size_t)bz * Cn * Tn;

  f32x4 acc[8][2];
  const f32x4 zero4 = {0.f, 0.f, 0.f, 0.f};
#pragma unroll
  for (int i = 0; i < 8; ++i)
#pragma unroll
    for (int j = 0; j < 2; ++j) acc[i][j] = zero4;

  const int srow = tid >> 3;
  const int schunk = (tid & 7) ^ (srow & 7);
  const unsigned short* Asrc = A + (size_t)(m0 + srow) * Kdim + schunk * 8;
  const unsigned short* Bsrc = Wp_ + (size_t)(n0 + srow) * Kdim + schunk * 8;

  auto STAGE_A = [&](int buf, int h, int t) {
    unsigned short* d = &L[buf][h * 8192 + tid * 8];
    const unsigned short* s = Asrc + (size_t)(h * 128) * Kdim + t * 64;
    gload_lds16(s, d);
    gload_lds16(s + (size_t)64 * Kdim, d + 4096);
  };
  auto STAGE_B = [&](int buf, int t) {
    unsigned short* d = &L[buf][16384 + tid * 8];
    const unsigned short* s = Bsrc + t * 64;
    gload_lds16(s, d);
    gload_lds16(s + (size_t)64 * Kdim, d + 4096);
  };

  const int pc0 = quad ^ (lr & 7);
  const int pc1 = (4 + quad) ^ (lr & 7);
  const int aoff = (wm * 128 + lr) * 64;
  const int boff = 16384 + (wn * 32 + lr) * 64;

  STAGE_A(0, 0, 0); STAGE_A(0, 1, 0);
  STAGE_B(0, 0);
  STAGE_B(1, 1);
  asm volatile("s_waitcnt vmcnt(2)" ::: "memory");
  G_BAR();

  short8 Af[4][2], Bf[2][2];

  for (int t = 0; t < NT; ++t) {
    const int cur = t & 1, nxt = cur ^ 1;
#pragma unroll
    for (int m = 0; m < 4; ++m) {
      Af[m][0] = *(const short8*)&L[cur][aoff + m * 1024 + pc0 * 8];
      Af[m][1] = *(const short8*)&L[cur][aoff + m * 1024 + pc1 * 8];
    }
#pragma unroll
    for (int n = 0; n < 2; ++n) {
      Bf[n][0] = *(const short8*)&L[cur][boff + n * 1024 + pc0 * 8];
      Bf[n][1] = *(const short8*)&L[cur][boff + n * 1024 + pc1 * 8];
    }
    if (t + 1 < NT) STAGE_A(nxt, 0, t + 1);
    G_BAR();
    __builtin_amdgcn_s_setprio(1);
#pragma unroll
    for (int m = 0; m < 4; ++m)
#pragma unroll
      for (int n = 0; n < 2; ++n) {
        G_MFMA(acc[m][n], Af[m][0], Bf[n][0]);
        G_MFMA(acc[m][n], Af[m][1], Bf[n][1]);
      }
    __builtin_amdgcn_s_setprio(0);
    G_BAR();
#pragma unroll
    for (int m = 0; m < 4; ++m) {
      Af[m][0] = *(const short8*)&L[cur][aoff + (m + 4) * 1024 + pc0 * 8];
      Af[m][1] = *(const short8*)&L[cur][aoff + (m + 4) * 1024 + pc1 * 8];
    }
    if (t + 1 < NT) STAGE_A(nxt, 1, t + 1);
    if (t + 2 < NT) STAGE_B(cur, t + 2);
    G_BAR();
    __builtin_amdgcn_s_setprio(1);
#pragma unroll
    for (int m = 0; m < 4; ++m)
#pragma unroll
      for (int n = 0; n < 2; ++n) {
        G_MFMA(acc[m + 4][n], Af[m][0], Bf[n][0]);
        G_MFMA(acc[m + 4][n], Af[m][1], Bf[n][1]);
      }
    __builtin_amdgcn_s_setprio(0);
    if (t < NT - 2) { asm volatile("s_waitcnt vmcnt(2)" ::: "memory"); }
    else            { asm volatile("s_waitcnt vmcnt(0)" ::: "memory"); }
    G_BAR();
  }

#pragma unroll
  for (int ni = 0; ni < 2; ++ni) {
    const int n = n0 + wn * 32 + ni * 16 + lr;
    const float bv = bias[n];
#pragma unroll
    for (int mi = 0; mi < 8; ++mi) {
#pragma unroll
      for (int r = 0; r < 4; ++r) {
        const int m = m0 + wm * 128 + mi * 16 + quad * 4 + r;
        Y[((size_t)bz * Tn + m) * Cn + n] = acc[mi][ni][r] + bv;
      }
    }
  }
}

// ---------------- flash attention: 8-wave kv-split (r7 passing version) ---
__global__ __launch_bounds__(512, 2) void attn_kernel(
    const unsigned short* __restrict__ Q,
    const unsigned short* __restrict__ K,
    const unsigned short* __restrict__ V,
    unsigned short* __restrict__ Ot) {
  constexpr int KST = 136;
  constexpr int VST = 136;   // 144 x 136 (rows 128..143 = ones)
  constexpr int PST = 136;   // 128 x 136 (4 bands x 32 rows)
  __shared__ unsigned short SMEM[54400];   // 108.8 KB
  unsigned short* Ks = SMEM;               // 128*136 = 17408
  unsigned short* Vs = SMEM + 17408;       // 144*136 = 19584
  unsigned short* Ps = SMEM + 36992;       // 128*136 = 17408

  const int tid = threadIdx.x;
  const int wave = tid >> 6, lane = tid & 63;
  const int wb = wave & 3;                 // q band
  const int wh = wave >> 2;                // kv half
  const int quad = lane >> 4, lr = lane & 15;
  const int bh = blockIdx.y;
  const float SL = 0.08838834764831845f * 1.4426950408889634f;  // scale*log2(e)

  const unsigned short* Kp = K + (size_t)bh * Tn * HD;
  const unsigned short* Vp = V + (size_t)bh * HD * Tn;
  unsigned short* Pw = &Ps[wb * 32 * PST];

  const int r = tid >> 2;
  const int cc = (tid & 3) * 32;
  unsigned short* kl = &Ks[r * KST + cc];
  unsigned short* vl = &Vs[r * VST + cc];
  u32x4 kreg[4], vreg[4];

  const f32x4 zero4 = {0.f, 0.f, 0.f, 0.f};
#pragma unroll 1
  for (int half = 0; half < 2; ++half) {
    const int jt = half ? (15 - (int)blockIdx.x) : (int)blockIdx.x;
    const int q0 = jt * 128;

    // re-init V "ones" rows each half (cbuf clobbers them in the combine)
    for (int i = tid; i < 16 * VST; i += 512) Vs[128 * VST + i] = 0x3F80;

    const unsigned short* Qp = Q + ((size_t)bh * Tn + q0 + wb * 32) * HD;
    short8 qf[2][4];
#pragma unroll
    for (int mi = 0; mi < 2; ++mi)
#pragma unroll
      for (int ks = 0; ks < 4; ++ks)
        qf[mi][ks] = *(const short8*)&Qp[(mi * 16 + lr) * HD + ks * 32 + quad * 8];

    f32x4 oacc[2][9];
#pragma unroll
    for (int mi = 0; mi < 2; ++mi)
#pragma unroll
      for (int nd = 0; nd < 9; ++nd) oacc[mi][nd] = zero4;

    const int nch = q0 / 128 + 1;

    {
      const unsigned short* kg = &Kp[(size_t)r * HD + cc];
      const unsigned short* vg = &Vp[(size_t)r * Tn + cc];
#pragma unroll
      for (int p = 0; p < 4; ++p) {
        kreg[p] = *(const u32x4*)(kg + p * 8);
        vreg[p] = *(const u32x4*)(vg + p * 8);
      }
    }

    for (int c = 0; c < nch; ++c) {
      const int k0 = c * 128;
#pragma unroll
      for (int p = 0; p < 4; ++p) {
        *(u32x4*)(kl + p * 8) = kreg[p];
        *(u32x4*)(vl + p * 8) = vreg[p];
      }
      __syncthreads();
      if (c + 1 < nch) {
        const int k1 = k0 + 128;
        const unsigned short* kg = &Kp[(size_t)(k1 + r) * HD + cc];
        const unsigned short* vg = &Vp[(size_t)r * Tn + k1 + cc];
#pragma unroll
        for (int p = 0; p < 4; ++p) {
          kreg[p] = *(const u32x4*)(kg + p * 8);
          vreg[p] = *(const u32x4*)(vg + p * 8);
        }
      }

      // QK^T for this wave's nt half (4 of 8 16-col tiles)
      f32x4 sa[2][4];
#pragma unroll
      for (int mi = 0; mi < 2; ++mi)
#pragma unroll
        for (int n4 = 0; n4 < 4; ++n4) sa[mi][n4] = zero4;
#pragma unroll
      for (int n4 = 0; n4 < 4; ++n4) {
        const int nt = wh * 4 + n4;
        short8 kf[4];
#pragma unroll
        for (int ks = 0; ks < 4; ++ks)
          kf[ks] = *(const short8*)&Ks[(nt * 16 + lr) * KST + ks * 32 + quad * 8];
#pragma unroll
        for (int mi = 0; mi < 2; ++mi)
#pragma unroll
          for (int ks = 0; ks < 4; ++ks)
            sa[mi][n4] = __builtin_amdgcn_mfma_f32_16x16x32_bf16(qf[mi][ks], kf[ks], sa[mi][n4], 0, 0, 0);
      }

      if (k0 == q0) {
#pragma unroll
        for (int mi = 0; mi < 2; ++mi)
#pragma unroll
          for (int n4 = 0; n4 < 4; ++n4)
#pragma unroll
            for (int r2 = 0; r2 < 4; ++r2) {
              const int qg = q0 + wb * 32 + mi * 16 + quad * 4 + r2;
              const int kg = k0 + (wh * 4 + n4) * 16 + lr;
              if (kg > qg) sa[mi][n4][r2] = -3.0e38f;
            }
      }

#pragma unroll
      for (int mi = 0; mi < 2; ++mi)
#pragma unroll
        for (int n4 = 0; n4 < 4; ++n4)
#pragma unroll
          for (int r2 = 0; r2 < 4; ++r2) {
            const float p = __builtin_amdgcn_exp2f(sa[mi][n4][r2] * SL);
            Pw[(mi * 16 + quad * 4 + r2) * PST + (wh * 4 + n4) * 16 + lr] = f2bf(p);
          }

      // PV over this wave's kt half (2 of 4 32-col k-slices) — intra-wave P
#pragma unroll
      for (int k2 = 0; k2 < 2; ++k2) {
        const int kt = wh * 2 + k2;
        short8 pf[2];
#pragma unroll
        for (int mi = 0; mi < 2; ++mi)
          pf[mi] = *(const short8*)&Pw[(mi * 16 + lr) * PST + kt * 32 + quad * 8];
#pragma unroll
        for (int nd = 0; nd < 9; ++nd) {
          short8 vf = *(const short8*)&Vs[(nd * 16 + lr) * VST + kt * 32 + quad * 8];
#pragma unroll
          for (int mi = 0; mi < 2; ++mi)
            oacc[mi][nd] = __builtin_amdgcn_mfma_f32_16x16x32_bf16(pf[mi], vf, oacc[mi][nd], 0, 0, 0);
        }
      }
      __syncthreads();
    }

    // ---- combine kv-partials: wh==1 publish to LDS (overlays dead Ks/Vs)
    f32x4* cbuf = (f32x4*)SMEM;   // 4608 x 16B = 73728 B (clobbers ones rows)
    if (wh == 1) {
#pragma unroll
      for (int mi = 0; mi < 2; ++mi)
#pragma unroll
        for (int nd = 0; nd < 9; ++nd)
          cbuf[(wb * 64 + lane) * 18 + mi * 9 + nd] = oacc[mi][nd];
    }
    __syncthreads();
    if (wh == 0) {
#pragma unroll
      for (int mi = 0; mi < 2; ++mi)
#pragma unroll
        for (int nd = 0; nd < 9; ++nd)
          oacc[mi][nd] += cbuf[(wb * 64 + lane) * 18 + mi * 9 + nd];
      // normalize + stage into Ps (t-major)
#pragma unroll
      for (int mi = 0; mi < 2; ++mi)
#pragma unroll
        for (int r2 = 0; r2 < 4; ++r2) {
          const float rl = 1.0f / oacc[mi][8][r2];
          const int tl = wb * 32 + mi * 16 + quad * 4 + r2;
#pragma unroll
          for (int nd = 0; nd < 8; ++nd)
            Ps[tl * PST + nd * 16 + lr] = f2bf(oacc[mi][nd][r2] * rl);
        }
    }
    __syncthreads();
    if (tid < 256) {
      unsigned short* Od = Ot + (size_t)bh * HD * Tn + q0;  // row = d, stride Tn
#pragma unroll
      for (int p = 0; p < 8; ++p) {
        const int d = p * 16 + (tid >> 4);
        const int t8 = (tid & 15) * 8;
        alignas(16) unsigned short v[8];
#pragma unroll
        for (int j = 0; j < 8; ++j) v[j] = Ps[(t8 + j) * PST + d];
        *(u32x4*)&Od[(size_t)d * Tn + t8] = *(const u32x4*)v;
      }
    }
    __syncthreads();
  }
}

extern "C" void kernel_launch(void* const* d_in, const int* in_sizes, int n_in,
                              void* d_out, int out_size, void* d_ws, size_t ws_size,
                              hipStream_t stream) {
  const float* x  = (const float*)d_in[0];
  const float* Wq = (const float*)d_in[1];
  const float* bq = (const float*)d_in[2];
  const float* Wk = (const float*)d_in[3];
  const float* bk = (const float*)d_in[4];
  const float* Wv = (const float*)d_in[5];
  const float* bv = (const float*)d_in[6];
  const float* Wp = (const float*)d_in[7];
  const float* bp = (const float*)d_in[8];
  float* out = (float*)d_out;

  char* ws = (char*)d_ws;
  const size_t MB = 1ull << 20;
  unsigned short* Xbf = (unsigned short*)(ws);             // 16MB
  unsigned short* Wqb = (unsigned short*)(ws + 16 * MB);   // 8MB each; Wq/Wk/Wv
  unsigned short* Wkb = (unsigned short*)(ws + 24 * MB);   //  CONTIGUOUS = W3
  unsigned short* Wvb = (unsigned short*)(ws + 32 * MB);
  unsigned short* Wpb = (unsigned short*)(ws + 40 * MB);
  unsigned short* Qb  = (unsigned short*)(ws + 48 * MB);   // 16MB
  unsigned short* Kb  = (unsigned short*)(ws + 64 * MB);   // 16MB
  unsigned short* Vtb = (unsigned short*)(ws + 80 * MB);   // 16MB (B,H,D,T)
  unsigned short* Otb = (unsigned short*)(ws + 96 * MB);   // 16MB (B,H*D,T)

  cast_bf16_kernel<<<dim3(1024), dim3(256), 0, stream>>>(x, Xbf, Bn * Tn * Cn);
  cast4_kernel<<<dim3(512, 4), dim3(256), 0, stream>>>(
      Wq, Wk, Wv, Wp, Wqb, Wkb, Wvb, Wpb, Cn * Cn);

  gemm_qkv_256x192_kernel<<<dim3(32, 16), dim3(512), 0, stream>>>(
      Xbf, Wqb /* = W3 base */, bq, bk, bv, Qb, Kb, Vtb);

  attn_kernel<<<dim3(8, Bn * NH), dim3(512), 0, stream>>>(Qb, Kb, Vtb, Otb);

  gemm_proj_256x128_kernel<<<dim3(16, 8, 2), dim3(512), 0, stream>>>(
      Otb, Wpb, bp, out);
}